// Round 13
// baseline (663.756 us; speedup 1.0000x reference)
//
#include <hip/hip_runtime.h>
#include <hip/hip_bf16.h>
#include <float.h>

static constexpr int BB  = 4;
static constexpr int NN  = 4096;
static constexpr int KSN = 16;
static constexpr int RN  = BB * NN;     // 16384 rows (b,n)
#define EPSBN 1e-5f

typedef __attribute__((ext_vector_type(8))) short short8;
typedef __attribute__((ext_vector_type(4))) short short4v;
typedef __attribute__((ext_vector_type(4))) float f32x4;

__device__ inline unsigned short f2bf(float f) {
  union { float f; unsigned u; } v; v.f = f;
  unsigned r = v.u + 0x7FFF + ((v.u >> 16) & 1);
  return (unsigned short)(r >> 16);
}
__device__ inline float bf2f(unsigned short h) {
  union { unsigned u; float f; } v; v.u = ((unsigned)h) << 16; return v.f;
}

// ---------------------------------------------------------------------------
// prep + gram fused (validated r10-r12).
// ---------------------------------------------------------------------------
__global__ __launch_bounds__(256) void prepgram_kernel(const float* __restrict__ data,
                                                       float4* __restrict__ pack,
                                                       float* __restrict__ partials) {
  const int t = blockIdx.x * 256 + threadIdx.x;   // RN
  const int lane = threadIdx.x & 63, wave = threadIdx.x >> 6;
  __shared__ float red[4][54];
  float d[9];
#pragma unroll
  for (int k = 0; k < 9; ++k) d[k] = data[(size_t)t * 9 + k];
  pack[t] = make_float4(d[0], d[1], d[2], fmaf(d[2], d[2], fmaf(d[1], d[1], d[0] * d[0])));
  int p = 0;
#pragma unroll
  for (int i = 0; i < 9; ++i) {
    float v = d[i];
#pragma unroll
    for (int mv = 1; mv < 64; mv <<= 1) v += __shfl_xor(v, mv);
    if (lane == 0) red[wave][p] = v;
    ++p;
  }
#pragma unroll
  for (int i = 0; i < 9; ++i)
#pragma unroll
    for (int j = i; j < 9; ++j) {
      float v = d[i] * d[j];
#pragma unroll
      for (int mv = 1; mv < 64; mv <<= 1) v += __shfl_xor(v, mv);
      if (lane == 0) red[wave][p] = v;
      ++p;
    }
  __syncthreads();
  if (threadIdx.x < 54)
    partials[blockIdx.x * 54 + threadIdx.x] =
        red[0][threadIdx.x] + red[1][threadIdx.x] + red[2][threadIdx.x] + red[3][threadIdx.x];
}

__global__ void fcstats_kernel(const float* __restrict__ partials,
                               const float* __restrict__ W, const float* __restrict__ bias,
                               float* __restrict__ S0) {
  __shared__ float g[54];
  const int t = threadIdx.x;   // 64 threads
  if (t < 54) {
    float s = 0.f;
    for (int b = 0; b < 64; ++b) s += partials[b * 54 + t];
    g[t] = s;
  }
  __syncthreads();
  float w[9];
#pragma unroll
  for (int k = 0; k < 9; ++k) w[k] = W[k * 64 + t];
  float b = bias[t];
  float dotw = 0.f;
#pragma unroll
  for (int k = 0; k < 9; ++k) dotw = fmaf(g[k], w[k], dotw);
  float s2 = 0.f;
  int p = 9;
#pragma unroll
  for (int i = 0; i < 9; ++i)
#pragma unroll
    for (int j = i; j < 9; ++j) {
      float gij = g[p++];
      s2 = fmaf(gij * ((i == j) ? 1.f : 2.f), w[i] * w[j], s2);
    }
  s2 += 2.f * b * dotw + (float)RN * b * b;
  S0[t] = dotw + (float)RN * b;
  S0[64 + t] = s2;
}

// ---------------------------------------------------------------------------
// weight-pack helpers.
// ---------------------------------------------------------------------------
__device__ inline void wpack_one(const float* __restrict__ W, unsigned short* __restrict__ wh,
                                 unsigned short* __restrict__ wl, int t, int lgC, int NK) {
  int k = t >> lgC, c = t & ((1 << lgC) - 1);
  float v = W[t];
  int ct = c >> 4, cl = c & 15, ks = k >> 5, kl = k & 31;
  int dst = ((ct * NK + ks) * 64 + (((kl >> 3) << 4) | cl)) * 8 + (kl & 7);
  unsigned short h = f2bf(v);
  wh[dst] = h; wl[dst] = f2bf(v - bf2f(h));
}
__device__ inline void diffpack_one(const float* __restrict__ W, unsigned short* __restrict__ wh,
                                    unsigned short* __restrict__ wl, int t) {
  int k = t >> 8, cc = t & 255;
  float v = W[k * 256 + cc] - W[(64 + k) * 256 + cc];  // Wtop - Wmid
  int ct = cc >> 4, cl = cc & 15, ks = k >> 5, kl = k & 31;
  int dst = ((ct * 2 + ks) * 64 + (((kl >> 3) << 4) | cl)) * 8 + (kl & 7);
  unsigned short h = f2bf(v);
  wh[dst] = h; wl[dst] = f2bf(v - bf2f(h));
}

// ---------------------------------------------------------------------------
// MEGA kernel (validated r11/r12): knn + fc_bnpack + megaprep.
// ---------------------------------------------------------------------------
__global__ __launch_bounds__(256) void mega_kernel(
    const float4* __restrict__ pack, int* __restrict__ idx,
    const float* __restrict__ data, const float* __restrict__ W_fc,
    const float* __restrict__ b_fc, const float* __restrict__ S0,
    unsigned short* __restrict__ xbh, unsigned short* __restrict__ xbl,
    const float* __restrict__ W1, const float* __restrict__ W4,
    const float* __restrict__ W2, const float* __restrict__ W3,
    const float* __restrict__ W5, const float* __restrict__ W6,
    const float* __restrict__ W10, const float* __restrict__ W11, const float* __restrict__ W12,
    unsigned short* __restrict__ W1mh, unsigned short* __restrict__ W1ml, float4* __restrict__ W1bt,
    unsigned short* __restrict__ W4mh, unsigned short* __restrict__ W4ml,
    unsigned short* __restrict__ W1ph, unsigned short* __restrict__ W1pl,
    unsigned short* __restrict__ W4ph, unsigned short* __restrict__ W4pl,
    unsigned short* __restrict__ W2h, unsigned short* __restrict__ W2l,
    unsigned short* __restrict__ W3h, unsigned short* __restrict__ W3l,
    unsigned short* __restrict__ W5h, unsigned short* __restrict__ W5l,
    unsigned short* __restrict__ W6h, unsigned short* __restrict__ W6l,
    unsigned short* __restrict__ W10h, unsigned short* __restrict__ W10l,
    unsigned short* __restrict__ W11xh, unsigned short* __restrict__ W11xl,
    unsigned short* __restrict__ W12h, unsigned short* __restrict__ W12l) {
  const int blk = blockIdx.x;
  if (blk < 4096) {
    // ------------------------------ KNN ------------------------------
    const int lane = threadIdx.x & 63;
    const int p = blk * 4 + (threadIdx.x >> 6);
    const int b = p >> 12;
    const float4* __restrict__ pb = pack + ((size_t)b << 12);
    const float4 me = pack[p];
    unsigned long long m0 = ~0ull, m1 = ~0ull, m2 = ~0ull, m3 = ~0ull;
#pragma unroll 8
    for (int s = 0; s < 64; ++s) {
      const float4 q = pb[s * 64 + lane];
      float d = me.w + q.w - 2.0f * fmaf(me.x, q.x, fmaf(me.y, q.y, me.z * q.z));
      unsigned ub = __float_as_uint(d);
      ub = (ub & 0x80000000u) ? ~ub : (ub | 0x80000000u);
      unsigned long long k = ((unsigned long long)ub << 12) | (unsigned)(s * 64 + lane);
      if (k < m3) {
        bool l0 = k < m0;  unsigned long long t0 = l0 ? m0 : k;  m0 = l0 ? k : m0;
        bool l1 = t0 < m1; unsigned long long t1 = l1 ? m1 : t0; m1 = l1 ? t0 : m1;
        bool l2 = t1 < m2; unsigned long long t2 = l2 ? m2 : t1; m2 = l2 ? t1 : m2;
        m3 = (t2 < m3) ? t2 : m3;
      }
    }
    for (int pass = 0; pass < 16; ++pass) {
      unsigned d0 = (unsigned)(m0 >> 12);
      unsigned w32 = d0;
#pragma unroll
      for (int mv = 1; mv < 64; mv <<= 1) {
        unsigned o = __shfl_xor(w32, mv);
        w32 = (o < w32) ? o : w32;
      }
      unsigned long long ball = __ballot(d0 == w32);
      unsigned widx;
      if (__popcll(ball) == 1) {
        widx = __shfl((unsigned)(m0 & 0xFFFull), (int)(__ffsll((long long)ball) - 1));
      } else {
        unsigned cand = (d0 == w32) ? (unsigned)(m0 & 0xFFFull) : 0xFFFFFFFFu;
#pragma unroll
        for (int mv = 1; mv < 64; mv <<= 1) {
          unsigned o = __shfl_xor(cand, mv);
          cand = (o < cand) ? o : cand;
        }
        widx = cand;
      }
      const unsigned long long w = ((unsigned long long)w32 << 12) | widx;
      if (lane == pass) idx[(p << 4) + pass] = (int)widx;
      if (m0 == w) { m0 = m1; m1 = m2; m2 = m3; m3 = ~0ull; }
      if (pass < 15 && __any(m0 == ~0ull)) {
        if (m0 == ~0ull) {                    // rare: rebuild from global
          m1 = ~0ull; m2 = ~0ull; m3 = ~0ull;
#pragma unroll 8
          for (int s = 0; s < 64; ++s) {
            const float4 q = pb[s * 64 + lane];
            float d = me.w + q.w - 2.0f * fmaf(me.x, q.x, fmaf(me.y, q.y, me.z * q.z));
            unsigned ub = __float_as_uint(d);
            ub = (ub & 0x80000000u) ? ~ub : (ub | 0x80000000u);
            unsigned long long k = ((unsigned long long)ub << 12) | (unsigned)(s * 64 + lane);
            k = (k > w) ? k : ~0ull;          // exclude consumed
            if (k < m3) {
              bool l0 = k < m0;  unsigned long long t0 = l0 ? m0 : k;  m0 = l0 ? k : m0;
              bool l1 = t0 < m1; unsigned long long t1 = l1 ? m1 : t0; m1 = l1 ? t0 : m1;
              bool l2 = t1 < m2; unsigned long long t2 = l2 ? m2 : t1; m2 = l2 ? t1 : m2;
              m3 = (t2 < m3) ? t2 : m3;
            }
          }
        }
      }
    }
  } else if (blk < 8192) {
    // --------------------------- fc + BN + pack ---------------------------
    const int t = (blk - 4096) * 256 + threadIdx.x;   // RN*64
    const int r = t >> 6, c = t & 63;
    const float* dr = data + (size_t)r * 9;
    float acc = b_fc[c];
#pragma unroll
    for (int k = 0; k < 9; ++k) acc = fmaf(dr[k], W_fc[k * 64 + c], acc);
    const float inv = 1.0f / RN;
    float m = S0[c] * inv;
    float v = fmaxf(S0[64 + c] * inv - m * m, 0.0f);
    float x = fmaxf((acc - m) * rsqrtf(v + EPSBN), 0.0f);
    unsigned short h = f2bf(x);
    xbh[t] = h; xbl[t] = f2bf(x - bf2f(h));
  } else {
    // ------------------------------ megaprep ------------------------------
    const int mb = blk - 8192;
    if (mb < 64) {
      int t = mb * 256 + threadIdx.x;
      int k = t >> 8, cc = t & 255;
      float w1mid = W1[(64 + k) * 256 + cc];
      unsigned short h1 = f2bf(w1mid);
      W1mh[cc * 64 + k] = h1;
      W1ml[cc * 64 + k] = f2bf(w1mid - bf2f(h1));
      float w4mid = W4[(64 + k) * 256 + cc];
      unsigned short h4 = f2bf(w4mid);
      W4mh[cc * 64 + k] = h4;
      W4ml[cc * 64 + k] = f2bf(w4mid - bf2f(h4));
      if (t < 256) W1bt[t] = make_float4(W1[128 * 256 + t], W1[129 * 256 + t], W1[130 * 256 + t], 0.f);
    } else if (mb < 128) {
      diffpack_one(W1, W1ph, W1pl, (mb - 64) * 256 + threadIdx.x);
    } else if (mb < 192) {
      diffpack_one(W4, W4ph, W4pl, (mb - 128) * 256 + threadIdx.x);
    } else if (mb < 256) {
      wpack_one(W2, W2h, W2l, (mb - 192) * 256 + threadIdx.x, 6, 8);
    } else if (mb < 272) {
      wpack_one(W3, W3h, W3l, (mb - 256) * 256 + threadIdx.x, 6, 2);
    } else if (mb < 336) {
      wpack_one(W5, W5h, W5l, (mb - 272) * 256 + threadIdx.x, 6, 8);
    } else if (mb < 352) {
      wpack_one(W6, W6h, W6l, (mb - 336) * 256 + threadIdx.x, 6, 2);
    } else if (mb < 864) {
      wpack_one(W10, W10h, W10l, (mb - 352) * 256 + threadIdx.x, 10, 4);
    } else if (mb < 1120) {
      wpack_one(W11 + 1024 * 512, W11xh, W11xl, (mb - 864) * 256 + threadIdx.x, 9, 4);
    } else {
      wpack_one(W12, W12h, W12l, (mb - 1120) * 256 + threadIdx.x, 8, 16);
    }
  }
}

// [x1|bn(x2)] -> fragment-major hi/lo pack (K=128) (validated r10-r12).
__global__ void pack_x12_kernel(const float* __restrict__ x1, const float* __restrict__ x2,
                                const float* __restrict__ S6,
                                unsigned short* __restrict__ ph, unsigned short* __restrict__ pl) {
  int t = blockIdx.x * 256 + threadIdx.x;   // RN*128
  int r = t >> 7, k = t & 127;
  float v;
  if (k < 64) {
    v = x1[(size_t)r * 64 + k];
  } else {
    int c = k - 64;
    const float inv = 1.0f / RN;
    float m = S6[c] * inv;
    float var = fmaxf(S6[64 + c] * inv - m * m, 0.f);
    v = fmaxf((x2[(size_t)r * 64 + c] - m) * rsqrtf(var + EPSBN), 0.f);
  }
  int rt = r >> 4, rl = r & 15, ks = k >> 5, kl = k & 31;
  int dst = ((rt * 4 + ks) * 64 + (((kl >> 3) << 4) | rl)) * 8 + (kl & 7);
  unsigned short h = f2bf(v);
  ph[dst] = h; pl[dst] = f2bf(v - bf2f(h));
}

// BN+ReLU on h11 (C=512) fused with fragment-major hi/lo pack
__global__ void bn_pack_kernel(const float* __restrict__ buf, const float* __restrict__ stats,
                               unsigned short* __restrict__ ph, unsigned short* __restrict__ pl) {
  int t = blockIdx.x * 256 + threadIdx.x;   // RN*512
  int c = t & 511, r = t >> 9;
  const float inv = 1.0f / RN;
  float m = stats[c] * inv;
  float v = fmaxf(stats[512 + c] * inv - m * m, 0.0f);
  float x = fmaxf((buf[t] - m) * rsqrtf(v + EPSBN), 0.0f);
  int rt = r >> 4, rl = r & 15, ks = c >> 5, kl = c & 31;
  int dst = ((rt * 16 + ks) * 64 + (((kl >> 3) << 4) | rl)) * 8 + (kl & 7);
  unsigned short h = f2bf(x);
  ph[dst] = h; pl[dst] = f2bf(x - bf2f(h));
}

// BN+ReLU in place (C=64) fused with row-major hi/lo write (x1v)
__global__ void bn_normpack_kernel(float* __restrict__ buf, const float* __restrict__ stats,
                                   unsigned short* __restrict__ hi, unsigned short* __restrict__ lo) {
  int t = blockIdx.x * 256 + threadIdx.x;   // RN*64
  int c = t & 63;
  const float inv = 1.0f / RN;
  float m = stats[c] * inv;
  float v = fmaxf(stats[64 + c] * inv - m * m, 0.0f);
  float x = fmaxf((buf[t] - m) * rsqrtf(v + EPSBN), 0.0f);
  buf[t] = x;
  unsigned short h = f2bf(x);
  hi[t] = h; lo[t] = f2bf(x - bf2f(h));
}

// ---------------------------------------------------------------------------
// Edge conv via MFMA with in-kernel basemat; r13: base tile lives in LDS
// (wave-private slice, no barriers), freeing 16 VGPRs and removing the
// per-point shfl broadcast. __launch_bounds__(256,4) caps VGPR at 128 so
// 4 waves/SIMD stay resident. Deferred-stats epilogue (r10).
// ---------------------------------------------------------------------------
template <bool HAS_PTS>
__global__ __launch_bounds__(256, 4) void edge_mfma_kernel(
    const unsigned short* __restrict__ Xh, const unsigned short* __restrict__ Xl,
    const int* __restrict__ idx,
    const float4* __restrict__ pack,
    const unsigned short* __restrict__ Wmh, const unsigned short* __restrict__ Wml,
    const unsigned short* __restrict__ Wph, const unsigned short* __restrict__ Wpl,
    const float4* __restrict__ Wbt,
    float* __restrict__ out, float* __restrict__ stats) {
  __shared__ float lds_base[4][16][64];   // [wave][point][col-local]  16 KB
  const int wave = threadIdx.x >> 6;
  const int lane = threadIdx.x & 63;
  const int pg   = blockIdx.x;
  const int c0   = wave << 6;
  const int cl   = lane & 15;
  const int kg   = (lane >> 4) << 3;
  const int bat  = pg >> 8;
  const int pbase = bat << 12;
  const int ib   = pg << 8;

  short8 bh[4][2], blo[4][2];
#pragma unroll
  for (int q = 0; q < 4; ++q) {
    const unsigned short* wp = Wmh + (size_t)(c0 + q * 16 + cl) * 64 + kg;
    bh[q][0] = *(const short8*)wp; bh[q][1] = *(const short8*)(wp + 32);
    const unsigned short* wq = Wml + (size_t)(c0 + q * 16 + cl) * 64 + kg;
    blo[q][0] = *(const short8*)wq; blo[q][1] = *(const short8*)(wq + 32);
  }
  float4 wb[4];
  if (HAS_PTS) {
#pragma unroll
    for (int q = 0; q < 4; ++q) wb[q] = Wbt[c0 + q * 16 + cl];
  }

  // ---- in-kernel basemat -> LDS (registers freed after this block) ----
  {
    const size_t xoff = ((size_t)((pg << 4) + cl)) * 64 + kg;   // row = own point
    short8 xa0h = *(const short8*)(Xh + xoff);
    short8 xa1h = *(const short8*)(Xh + xoff + 32);
    short8 xa0l = *(const short8*)(Xl + xoff);
    short8 xa1l = *(const short8*)(Xl + xoff + 32);
#pragma unroll
    for (int q = 0; q < 4; ++q) {
      f32x4 base = {0.f, 0.f, 0.f, 0.f};
      const int ct = wave * 4 + q;
      const size_t w0 = (((size_t)ct * 2 + 0) * 64 + lane) * 8;
      const size_t w1 = (((size_t)ct * 2 + 1) * 64 + lane) * 8;
      short8 p0h = *(const short8*)(Wph + w0);
      short8 p0l = *(const short8*)(Wpl + w0);
      short8 p1h = *(const short8*)(Wph + w1);
      short8 p1l = *(const short8*)(Wpl + w1);
      base = __builtin_amdgcn_mfma_f32_16x16x32_bf16(xa0l, p0h, base, 0, 0, 0);
      base = __builtin_amdgcn_mfma_f32_16x16x32_bf16(xa0h, p0l, base, 0, 0, 0);
      base = __builtin_amdgcn_mfma_f32_16x16x32_bf16(xa0h, p0h, base, 0, 0, 0);
      base = __builtin_amdgcn_mfma_f32_16x16x32_bf16(xa1l, p1h, base, 0, 0, 0);
      base = __builtin_amdgcn_mfma_f32_16x16x32_bf16(xa1h, p1l, base, 0, 0, 0);
      base = __builtin_amdgcn_mfma_f32_16x16x32_bf16(xa1h, p1h, base, 0, 0, 0);
#pragma unroll
      for (int i = 0; i < 4; ++i)
        lds_base[wave][((lane >> 4) << 2) + i][q * 16 + cl] = base[i];
    }
  }

  float P1[4] = {0.f, 0.f, 0.f, 0.f}, P2[4] = {0.f, 0.f, 0.f, 0.f};
  float PCx[4] = {0.f, 0.f, 0.f, 0.f};
  float PB1[4] = {0.f, 0.f, 0.f, 0.f}, PB2[4] = {0.f, 0.f, 0.f, 0.f};

  int jn = idx[ib + 16 + cl];
  int j0 = idx[ib + cl];
  size_t ro = ((size_t)(pbase | j0) << 6) + kg;
  short8 a0h = *(const short8*)(Xh + ro);
  short8 a1h = *(const short8*)(Xh + ro + 32);
  short8 a0l = *(const short8*)(Xl + ro);
  short8 a1l = *(const short8*)(Xl + ro + 32);

  for (int pp = 0; pp < 16; ++pp) {
    const int p = (pg << 4) | pp;
    int jf = 0;
    if (pp < 14) jf = idx[ib + ((pp + 2) << 4) + cl];
    short8 n0h, n1h, n0l, n1l;
    if (pp < 15) {
      size_t rn = ((size_t)(pbase | jn) << 6) + kg;
      n0h = *(const short8*)(Xh + rn);
      n1h = *(const short8*)(Xh + rn + 32);
      n0l = *(const short8*)(Xl + rn);
      n1l = *(const short8*)(Xl + rn + 32);
    }
    float dx0, dy0, dz0, dx1, dy1, dz1, dx2, dy2, dz2, dx3, dy3, dz3;
    if (HAS_PTS) {
      const int4 j4 = *(const int4*)(idx + (p << 4) + ((lane >> 4) << 2));
      const float4 pc = pack[p];
      const float4 q0 = pack[pbase | j4.x];
      const float4 q1 = pack[pbase | j4.y];
      const float4 q2 = pack[pbase | j4.z];
      const float4 q3 = pack[pbase | j4.w];
      dx0 = q0.x - pc.x; dy0 = q0.y - pc.y; dz0 = q0.z - pc.z;
      dx1 = q1.x - pc.x; dy1 = q1.y - pc.y; dz1 = q1.z - pc.z;
      dx2 = q2.x - pc.x; dy2 = q2.y - pc.y; dz2 = q2.z - pc.z;
      dx3 = q3.x - pc.x; dy3 = q3.y - pc.y; dz3 = q3.z - pc.z;
    }
    f32x4 acc[4];
#pragma unroll
    for (int q = 0; q < 4; ++q) {
      acc[q][0] = 0.f; acc[q][1] = 0.f; acc[q][2] = 0.f; acc[q][3] = 0.f;
    }
#pragma unroll
    for (int q = 0; q < 4; ++q) {
      acc[q] = __builtin_amdgcn_mfma_f32_16x16x32_bf16(a0l, bh[q][0], acc[q], 0, 0, 0);
      acc[q] = __builtin_amdgcn_mfma_f32_16x16x32_bf16(a1l, bh[q][1], acc[q], 0, 0, 0);
      acc[q] = __builtin_amdgcn_mfma_f32_16x16x32_bf16(a0h, blo[q][0], acc[q], 0, 0, 0);
      acc[q] = __builtin_amdgcn_mfma_f32_16x16x32_bf16(a1h, blo[q][1], acc[q], 0, 0, 0);
      acc[q] = __builtin_amdgcn_mfma_f32_16x16x32_bf16(a0h, bh[q][0], acc[q], 0, 0, 0);
      acc[q] = __builtin_amdgcn_mfma_f32_16x16x32_bf16(a1h, bh[q][1], acc[q], 0, 0, 0);
    }
    if (HAS_PTS) {
#pragma unroll
      for (int q = 0; q < 4; ++q) {
        acc[q][0] += dx0 * wb[q].x + dy0 * wb[q].y + dz0 * wb[q].z;
        acc[q][1] += dx1 * wb[q].x + dy1 * wb[q].y + dz1 * wb[q].z;
        acc[q][2] += dx2 * wb[q].x + dy2 * wb[q].y + dz2 * wb[q].z;
        acc[q][3] += dx3 * wb[q].x + dy3 * wb[q].y + dz3 * wb[q].z;
      }
    }
#pragma unroll
    for (int q = 0; q < 4; ++q) {
      float s1p = acc[q][0] + acc[q][1] + acc[q][2] + acc[q][3];
      float s2p = acc[q][0] * acc[q][0] + acc[q][1] * acc[q][1]
                + acc[q][2] * acc[q][2] + acc[q][3] * acc[q][3];
      float mx = fmaxf(fmaxf(acc[q][0], acc[q][1]), fmaxf(acc[q][2], acc[q][3]));
      mx = fmaxf(mx, __shfl_xor(mx, 16));
      mx = fmaxf(mx, __shfl_xor(mx, 32));
      float bb = lds_base[wave][pp][q * 16 + cl];
      if (lane < 16) out[(size_t)p * 256 + c0 + q * 16 + cl] = mx + bb;
      P1[q] += s1p;
      P2[q] += s2p;
      PCx[q] = fmaf(bb, s1p, PCx[q]);
      PB1[q] += bb;
      PB2[q] = fmaf(bb, bb, PB2[q]);
    }
    a0h = n0h; a1h = n1h; a0l = n0l; a1l = n1l;
    jn = jf;
  }
#pragma unroll
  for (int q = 0; q < 4; ++q) {
    float p1 = P1[q]; p1 += __shfl_xor(p1, 16); p1 += __shfl_xor(p1, 32);
    float p2 = P2[q]; p2 += __shfl_xor(p2, 16); p2 += __shfl_xor(p2, 32);
    float pc = PCx[q]; pc += __shfl_xor(pc, 16); pc += __shfl_xor(pc, 32);
    if (lane < 16) {
      atomicAdd(&stats[c0 + q * 16 + lane], p1 + 16.f * PB1[q]);
      atomicAdd(&stats[256 + c0 + q * 16 + lane], p2 + 2.f * pc + 16.f * PB2[q]);
    }
  }
}

// ---------------------------------------------------------------------------
// agg_pack (validated r10-r12): bn_relu(max over 16 nb) -> packed hi/lo.
// ---------------------------------------------------------------------------
template <int LGC>
__global__ __launch_bounds__(256) void agg_pack_kernel(
    const float* __restrict__ X, const int* __restrict__ idx,
    const float* __restrict__ stats, float inv_cnt,
    unsigned short* __restrict__ ph, unsigned short* __restrict__ pl) {
  const int C = 1 << LGC;
  const int xcd = blockIdx.x & 7, bat = xcd >> 1;
  const int j = ((blockIdx.x >> 3) << 1) | (xcd & 1);
  const int rows_per_block = 256 >> (LGC - 2);
  const int r = bat * 4096 + j * rows_per_block + (threadIdx.x >> (LGC - 2));
  const int cq = threadIdx.x & ((C >> 2) - 1);
  const int base = bat << 12;
  const int* ip = idx + (size_t)r * KSN;
  float4 mx = make_float4(-FLT_MAX, -FLT_MAX, -FLT_MAX, -FLT_MAX);
#pragma unroll
  for (int k = 0; k < KSN; ++k) {
    int jj = ip[k];
    const float4 v = *reinterpret_cast<const float4*>(X + (size_t)(base + jj) * C + cq * 4);
    mx.x = fmaxf(mx.x, v.x); mx.y = fmaxf(mx.y, v.y);
    mx.z = fmaxf(mx.z, v.z); mx.w = fmaxf(mx.w, v.w);
  }
  const int c = cq * 4;
  const float4 sa = *reinterpret_cast<const float4*>(stats + c);
  const float4 sb = *reinterpret_cast<const float4*>(stats + C + c);
  float m0 = sa.x * inv_cnt, m1 = sa.y * inv_cnt, m2 = sa.z * inv_cnt, m3 = sa.w * inv_cnt;
  float o0 = fmaxf((mx.x - m0) * rsqrtf(fmaxf(sb.x * inv_cnt - m0 * m0, 0.f) + EPSBN), 0.f);
  float o1 = fmaxf((mx.y - m1) * rsqrtf(fmaxf(sb.y * inv_cnt - m1 * m1, 0.f) + EPSBN), 0.f);
  float o2 = fmaxf((mx.z - m2) * rsqrtf(fmaxf(sb.z * inv_cnt - m2 * m2, 0.f) + EPSBN), 0.f);
  float o3 = fmaxf((mx.w - m3) * rsqrtf(fmaxf(sb.w * inv_cnt - m3 * m3, 0.f) + EPSBN), 0.f);
  short4v H, L;
  H.x = (short)f2bf(o0); L.x = (short)f2bf(o0 - bf2f((unsigned short)H.x));
  H.y = (short)f2bf(o1); L.y = (short)f2bf(o1 - bf2f((unsigned short)H.y));
  H.z = (short)f2bf(o2); L.z = (short)f2bf(o2 - bf2f((unsigned short)H.z));
  H.w = (short)f2bf(o3); L.w = (short)f2bf(o3 - bf2f((unsigned short)H.w));
  const int NK = C >> 5;
  const int rt = r >> 4, rl = r & 15, ks = c >> 5, kl = c & 31;
  const size_t dst = (((size_t)rt * NK + ks) * 64 + (((kl >> 3) << 4) | rl)) * 8 + (kl & 7);
  *(short4v*)(ph + dst) = H;
  *(short4v*)(pl + dst) = L;
}

// ---------------------------------------------------------------------------
// MFMA GEMM (validated r7-r12): wave = 64 rows x 64 cols, acc[4][4].
// ---------------------------------------------------------------------------
template <int AMODE, bool DOMAX, bool BIAS>
__global__ __launch_bounds__(256) void gemm_mfma_kernel(
    const unsigned short* __restrict__ Ah, const unsigned short* __restrict__ Al,
    const unsigned short* __restrict__ Wh, const unsigned short* __restrict__ Wl,
    float* __restrict__ Y, float* __restrict__ pmax, float* __restrict__ stats,
    const float* __restrict__ gbias,
    int K, int C) {
  __shared__ float red1[4][64], red2[4][64], redm[4][64];
  const int wave = threadIdx.x >> 6, lane = threadIdx.x & 63;
  const int rtb = blockIdx.x * 16 + wave * 4;
  const int c0  = blockIdx.y * 64;
  const int ct0 = blockIdx.y * 4;
  const int NK  = K >> 5;
  const int bat = blockIdx.x >> 4;
  f32x4 acc[4][4];
#pragma unroll
  for (int r = 0; r < 4; ++r)
#pragma unroll
    for (int cc = 0; cc < 4; ++cc) {
      acc[r][cc][0] = 0.f; acc[r][cc][1] = 0.f; acc[r][cc][2] = 0.f; acc[r][cc][3] = 0.f;
    }
  const int lhalf = (lane >> 4) << 3;
  for (int ks = 0; ks < NK; ++ks) {
    short8 ah[4], al[4];
    if (AMODE == 1) {
#pragma unroll
      for (int r = 0; r < 4; ++r) {
        const size_t aoff = ((size_t)((rtb + r) * 16 + (lane & 15))) * 64 + ks * 32 + lhalf;
        ah[r] = *(const short8*)(Ah + aoff);
        al[r] = *(const short8*)(Al + aoff);
      }
    } else {
#pragma unroll
      for (int r = 0; r < 4; ++r) {
        const size_t aoff = (((size_t)(rtb + r) * NK + ks) * 64 + lane) * 8;
        ah[r] = *(const short8*)(Ah + aoff);
        al[r] = *(const short8*)(Al + aoff);
      }
    }
#pragma unroll
    for (int cc = 0; cc < 4; ++cc) {
      const size_t woff = (((size_t)(ct0 + cc) * NK + ks) * 64 + lane) * 8;
      short8 bh = *(const short8*)(Wh + woff);
      short8 bl = *(const short8*)(Wl + woff);
#pragma unroll
      for (int r = 0; r < 4; ++r) {
        acc[r][cc] = __builtin_amdgcn_mfma_f32_16x16x32_bf16(al[r], bh, acc[r][cc], 0, 0, 0);
        acc[r][cc] = __builtin_amdgcn_mfma_f32_16x16x32_bf16(ah[r], bl, acc[r][cc], 0, 0, 0);
        acc[r][cc] = __builtin_amdgcn_mfma_f32_16x16x32_bf16(ah[r], bh, acc[r][cc], 0, 0, 0);
      }
    }
  }
#pragma unroll
  for (int cc = 0; cc < 4; ++cc) {
    float bv = 0.f;
    if (BIAS) bv = gbias[(size_t)bat * C + c0 + cc * 16 + (lane & 15)];
    float s1 = 0.f, s2 = 0.f, mm = -FLT_MAX;
#pragma unroll
    for (int r = 0; r < 4; ++r) {
#pragma unroll
      for (int i = 0; i < 4; ++i) {
        float v = acc[r][cc][i] + bv;
        if (!DOMAX)
          Y[(size_t)((rtb + r) * 16 + ((lane >> 4) << 2) + i) * C + c0 + cc * 16 + (lane & 15)] = v;
        s1 += v; s2 = fmaf(v, v, s2); mm = fmaxf(mm, v);
      }
    }
    s1 += __shfl_xor(s1, 16); s1 += __shfl_xor(s1, 32);
    s2 += __shfl_xor(s2, 16); s2 += __shfl_xor(s2, 32);
    mm = fmaxf(mm, __shfl_xor(mm, 16)); mm = fmaxf(mm, __shfl_xor(mm, 32));
    if (lane < 16) {
      red1[wave][cc * 16 + lane] = s1;
      red2[wave][cc * 16 + lane] = s2;
      if (DOMAX) redm[wave][cc * 16 + lane] = mm;
    }
  }
  __syncthreads();
  if (threadIdx.x < 64) {
    const int t = threadIdx.x;
    float a = red1[0][t] + red1[1][t] + red1[2][t] + red1[3][t];
    float b = red2[0][t] + red2[1][t] + red2[2][t] + red2[3][t];
    atomicAdd(&stats[c0 + t], a);
    atomicAdd(&stats[C + c0 + t], b);
    if (DOMAX) {
      float mm = fmaxf(fmaxf(redm[0][t], redm[1][t]), fmaxf(redm[2][t], redm[3][t]));
      pmax[(size_t)blockIdx.x * C + c0 + t] = mm;
    }
  }
}

// ---------------------------------------------------------------------------
// fin_g + gb11 fused (validated r12).
// ---------------------------------------------------------------------------
__global__ __launch_bounds__(256) void fing_gb_kernel(const float* __restrict__ pmax,
                                                      const float* __restrict__ S7,
                                                      const float* __restrict__ W11,
                                                      float* __restrict__ gb) {
  __shared__ float g_lds[1024];
  const int t = threadIdx.x;
  const int b = blockIdx.x >> 1, ch = blockIdx.x & 1;
  const float inv = 1.0f / 16384.0f;
#pragma unroll
  for (int kk = 0; kk < 4; ++kk) {
    int c = kk * 256 + t;
    float m = S7[c] * inv;
    float v = fmaxf(S7[1024 + c] * inv - m * m, 0.0f);
    float rs = rsqrtf(v + EPSBN);
    float mx = -FLT_MAX;
    for (int s = 0; s < 16; ++s) mx = fmaxf(mx, pmax[(size_t)(b * 16 + s) * 1024 + c]);
    g_lds[c] = fmaxf((mx - m) * rs, 0.0f);
  }
  __syncthreads();
  const int c_out = ch * 256 + t;
  float acc = 0.f;
#pragma unroll 8
  for (int k = 0; k < 1024; ++k) acc = fmaf(g_lds[k], W11[(size_t)k * 512 + c_out], acc);
  gb[b * 512 + c_out] = acc;
}

// final13 with fused BN(h12) (validated r10-r12)
__global__ __launch_bounds__(256) void final13_kernel(const float* __restrict__ h,
                                                      const float* __restrict__ S9,
                                                      const float* __restrict__ W,
                                                      float* __restrict__ out) {
  __shared__ float wl[256 * 13];
  __shared__ float ms[256], rs[256];
  const int t = threadIdx.x;
  {
    const float inv = 1.0f / RN;
    float m = S9[t] * inv;
    float v = fmaxf(S9[256 + t] * inv - m * m, 0.0f);
    ms[t] = m; rs[t] = rsqrtf(v + EPSBN);
#pragma unroll
    for (int i = 0; i < 13; ++i) wl[t * 13 + i] = W[t * 13 + i];
  }
  __syncthreads();
  const int r = blockIdx.x * 16 + (t >> 4);
  const int c = t & 15;
  const int ci = (c < 13) ? c : 0;
  const float* hr = h + (size_t)r * 256;
  float acc = 0.0f;
  for (int k = 0; k < 256; ++k) {
    float x = fmaxf((hr[k] - ms[k]) * rs[k], 0.0f);
    acc = fmaf(x, wl[k * 13 + ci], acc);
  }
  if (c < 13) {
    int b = r >> 12, n = r & 4095;
    out[(size_t)b * 13 * NN + (size_t)c * NN + n] = acc;
  }
}

// ---------------------------------------------------------------------------
extern "C" void kernel_launch(void* const* d_in, const int* in_sizes, int n_in,
                              void* d_out, int out_size, void* d_ws, size_t ws_size,
                              hipStream_t stream) {
  (void)in_sizes; (void)n_in; (void)out_size; (void)ws_size;
  const float* data = (const float*)d_in[0];
  const float* W_fc = (const float*)d_in[1];
  const float* b_fc = (const float*)d_in[2];
  const float* W1   = (const float*)d_in[3];
  const float* W2   = (const float*)d_in[4];
  const float* W3   = (const float*)d_in[5];
  const float* W4   = (const float*)d_in[6];
  const float* W5   = (const float*)d_in[7];
  const float* W6   = (const float*)d_in[8];
  const float* W10  = (const float*)d_in[9];
  const float* W11  = (const float*)d_in[10];
  const float* W12  = (const float*)d_in[11];
  const float* W13  = (const float*)d_in[12];
  float* out = (float*)d_out;

  float* ws  = (float*)d_ws;
  int*   idx = (int*)d_ws;
  size_t o = 262144;
  float* x0   = ws + o; o += (size_t)RN * 64;     // dead fp32; hosts x12l overlay
  float* x1v  = ws + o; o += (size_t)RN * 64;
  float* x2v  = ws + o; o += (size_t)RN * 64;
  float* bufA = ws + o; o += (size_t)RN * 256;
  float* bufB = ws + o; o += (size_t)RN * 256;    // hosts h11l overlay
  float* bufC = ws + o; o += (size_t)RN * 64;
  float* pmax = ws + o; o += (size_t)64 * 1024;
  float* h11  = ws + o; o += (size_t)RN * 512;
  float* h12  = ws + o; o += (size_t)RN * 256;
  float* stats = ws + o; o += 8192;
  float4* pack = (float4*)(ws + o); o += (size_t)RN * 4;
  unsigned short* xbh = (unsigned short*)(ws + o); o += (size_t)RN * 32;
  unsigned short* xbl = (unsigned short*)(ws + o); o += (size_t)RN * 32;
  unsigned short* W1mh = (unsigned short*)(ws + o); o += 8192;
  unsigned short* W1ml = (unsigned short*)(ws + o); o += 8192;
  unsigned short* W4mh = (unsigned short*)(ws + o); o += 8192;
  unsigned short* W4ml = (unsigned short*)(ws + o); o += 8192;
  float4* W1bt = (float4*)(ws + o); o += 1024;
  unsigned short* W10h = (unsigned short*)(ws + o); o += 65536;
  unsigned short* W10l = (unsigned short*)(ws + o); o += 65536;
  unsigned short* W11xh = (unsigned short*)(ws + o); o += 32768;
  unsigned short* W11xl = (unsigned short*)(ws + o); o += 32768;
  unsigned short* W12h = (unsigned short*)(ws + o); o += 65536;
  unsigned short* W12l = (unsigned short*)(ws + o); o += 65536;
  float* gb = ws + o; o += 2048;
  unsigned short* W1ph = (unsigned short*)(ws + o); o += 8192;
  unsigned short* W1pl = (unsigned short*)(ws + o); o += 8192;
  unsigned short* W4ph = (unsigned short*)(ws + o); o += 8192;
  unsigned short* W4pl = (unsigned short*)(ws + o); o += 8192;
  unsigned short* W2h  = (unsigned short*)(ws + o); o += 8192;
  unsigned short* W2l  = (unsigned short*)(ws + o); o += 8192;
  unsigned short* W3h  = (unsigned short*)(ws + o); o += 2048;
  unsigned short* W3l  = (unsigned short*)(ws + o); o += 2048;
  unsigned short* W5h  = (unsigned short*)(ws + o); o += 8192;
  unsigned short* W5l  = (unsigned short*)(ws + o); o += 8192;
  unsigned short* W6h  = (unsigned short*)(ws + o); o += 2048;
  unsigned short* W6l  = (unsigned short*)(ws + o); o += 2048;
  float* gpart = ws + o; o += 64 * 54;
  // overlays on dead buffers:
  unsigned short* x12h = (unsigned short*)bufC;
  unsigned short* x12l = (unsigned short*)x0;
  unsigned short* h11h = (unsigned short*)bufA;
  unsigned short* h11l = (unsigned short*)bufB;
  unsigned short* aggh = (unsigned short*)h11;
  unsigned short* aggl = (unsigned short*)h11 + (size_t)RN * 256;

  float* S0 = stats;          // 64 (fc)
  float* S1 = stats + 128;    // 256 (edge1)
  float* S2 = stats + 640;    // 64  (W2)
  float* S3 = stats + 768;    // 64  (W3)
  float* S4 = stats + 896;    // 256 (edge2)
  float* S5 = stats + 1408;   // 64  (W5)
  float* S6 = stats + 1536;   // 64  (W6)
  float* S7 = stats + 1664;   // 1024 (W10)
  float* S8 = stats + 3712;   // 512 (W11)
  float* S9 = stats + 4736;   // 256 (W12)

  hipMemsetAsync(stats, 0, 8192 * sizeof(float), stream);

  prepgram_kernel<<<64, 256, 0, stream>>>(data, pack, gpart);
  fcstats_kernel<<<1, 64, 0, stream>>>(gpart, W_fc, b_fc, S0);

  // MEGA: knn (4096 blocks) + fc_bnpack (4096) + megaprep (1632)
  mega_kernel<<<9824, 256, 0, stream>>>(
      pack, idx, data, W_fc, b_fc, S0, xbh, xbl,
      W1, W4, W2, W3, W5, W6, W10, W11, W12,
      W1mh, W1ml, W1bt, W4mh, W4ml,
      W1ph, W1pl, W4ph, W4pl, W2h, W2l, W3h, W3l, W5h, W5l, W6h, W6l,
      W10h, W10l, W11xh, W11xl, W12h, W12l);

  // edge conv 1 (basemat computed in-kernel, base tile in LDS)
  edge_mfma_kernel<true><<<1024, 256, 0, stream>>>(
      xbh, xbl, idx, pack, W1mh, W1ml, W1ph, W1pl, W1bt, bufA, S1);

  // graph conv 1
  agg_pack_kernel<8><<<4096, 256, 0, stream>>>(bufA, idx, S1, 1.0f / (RN * 16), aggh, aggl);
  gemm_mfma_kernel<0, false, false><<<dim3(64, 1), 256, 0, stream>>>(
      aggh, aggl, W2h, W2l, bufC, nullptr, S2, nullptr, 256, 64);

  // graph conv 2
  agg_pack_kernel<6><<<1024, 256, 0, stream>>>(bufC, idx, S2, 1.0f / RN, aggh, aggl);
  gemm_mfma_kernel<0, false, false><<<dim3(64, 1), 256, 0, stream>>>(
      aggh, aggl, W3h, W3l, x1v, nullptr, S3, nullptr, 64, 64);
  bn_normpack_kernel<<<RN * 64 / 256, 256, 0, stream>>>(x1v, S3, xbh, xbl);

  // edge conv 2 (no pts; basemat in-kernel, base tile in LDS)
  edge_mfma_kernel<false><<<1024, 256, 0, stream>>>(
      xbh, xbl, idx, pack, W4mh, W4ml, W4ph, W4pl, nullptr, bufA, S4);

  // graph conv 3
  agg_pack_kernel<8><<<4096, 256, 0, stream>>>(bufA, idx, S4, 1.0f / (RN * 16), aggh, aggl);
  gemm_mfma_kernel<0, false, false><<<dim3(64, 1), 256, 0, stream>>>(
      aggh, aggl, W5h, W5l, bufC, nullptr, S5, nullptr, 256, 64);

  // graph conv 4 -> x2v raw (+S6); bn fused into pack_x12
  agg_pack_kernel<6><<<1024, 256, 0, stream>>>(bufC, idx, S5, 1.0f / RN, aggh, aggl);
  gemm_mfma_kernel<0, false, false><<<dim3(64, 1), 256, 0, stream>>>(
      aggh, aggl, W6h, W6l, x2v, nullptr, S6, nullptr, 64, 64);

  // pack [x1|bn(x2)]
  pack_x12_kernel<<<RN * 128 / 256, 256, 0, stream>>>(x1v, x2v, S6, x12h, x12l);

  // W10 path
  gemm_mfma_kernel<0, true, false><<<dim3(64, 16), 256, 0, stream>>>(
      x12h, x12l, W10h, W10l, nullptr, pmax, S7, nullptr, 128, 1024);

  // fused fin_g + gb11
  fing_gb_kernel<<<8, 256, 0, stream>>>(pmax, S7, W11, gb);

  // W11: K=128 MFMA gemm + per-batch g-bias
  gemm_mfma_kernel<0, false, true><<<dim3(64, 8), 256, 0, stream>>>(
      x12h, x12l, W11xh, W11xl, h11, nullptr, S8, gb, 128, 512);
  bn_pack_kernel<<<RN * 512 / 256, 256, 0, stream>>>(h11, S8, h11h, h11l);

  // W12 -> h12 raw (+S9); bn fused into final13
  gemm_mfma_kernel<0, false, false><<<dim3(64, 4), 256, 0, stream>>>(
      h11h, h11l, W12h, W12l, h12, nullptr, S9, nullptr, 512, 256);

  final13_kernel<<<RN / 16, 256, 0, stream>>>(h12, S9, W13, out);
}

// Round 14
// 545.813 us; speedup vs baseline: 1.2161x; 1.2161x over previous
//
#include <hip/hip_runtime.h>
#include <hip/hip_bf16.h>
#include <float.h>

static constexpr int BB  = 4;
static constexpr int NN  = 4096;
static constexpr int KSN = 16;
static constexpr int RN  = BB * NN;     // 16384 rows (b,n)
#define EPSBN 1e-5f

typedef __attribute__((ext_vector_type(8))) short short8;
typedef __attribute__((ext_vector_type(4))) short short4v;
typedef __attribute__((ext_vector_type(4))) float f32x4;

__device__ inline unsigned short f2bf(float f) {
  union { float f; unsigned u; } v; v.f = f;
  unsigned r = v.u + 0x7FFF + ((v.u >> 16) & 1);
  return (unsigned short)(r >> 16);
}
__device__ inline float bf2f(unsigned short h) {
  union { unsigned u; float f; } v; v.u = ((unsigned)h) << 16; return v.f;
}

// ---------------------------------------------------------------------------
// prep + gram fused (validated r10-r13).
// ---------------------------------------------------------------------------
__global__ __launch_bounds__(256) void prepgram_kernel(const float* __restrict__ data,
                                                       float4* __restrict__ pack,
                                                       float* __restrict__ partials) {
  const int t = blockIdx.x * 256 + threadIdx.x;   // RN
  const int lane = threadIdx.x & 63, wave = threadIdx.x >> 6;
  __shared__ float red[4][54];
  float d[9];
#pragma unroll
  for (int k = 0; k < 9; ++k) d[k] = data[(size_t)t * 9 + k];
  pack[t] = make_float4(d[0], d[1], d[2], fmaf(d[2], d[2], fmaf(d[1], d[1], d[0] * d[0])));
  int p = 0;
#pragma unroll
  for (int i = 0; i < 9; ++i) {
    float v = d[i];
#pragma unroll
    for (int mv = 1; mv < 64; mv <<= 1) v += __shfl_xor(v, mv);
    if (lane == 0) red[wave][p] = v;
    ++p;
  }
#pragma unroll
  for (int i = 0; i < 9; ++i)
#pragma unroll
    for (int j = i; j < 9; ++j) {
      float v = d[i] * d[j];
#pragma unroll
      for (int mv = 1; mv < 64; mv <<= 1) v += __shfl_xor(v, mv);
      if (lane == 0) red[wave][p] = v;
      ++p;
    }
  __syncthreads();
  if (threadIdx.x < 54)
    partials[blockIdx.x * 54 + threadIdx.x] =
        red[0][threadIdx.x] + red[1][threadIdx.x] + red[2][threadIdx.x] + red[3][threadIdx.x];
}

__global__ void fcstats_kernel(const float* __restrict__ partials,
                               const float* __restrict__ W, const float* __restrict__ bias,
                               float* __restrict__ S0) {
  __shared__ float g[54];
  const int t = threadIdx.x;   // 64 threads
  if (t < 54) {
    float s = 0.f;
    for (int b = 0; b < 64; ++b) s += partials[b * 54 + t];
    g[t] = s;
  }
  __syncthreads();
  float w[9];
#pragma unroll
  for (int k = 0; k < 9; ++k) w[k] = W[k * 64 + t];
  float b = bias[t];
  float dotw = 0.f;
#pragma unroll
  for (int k = 0; k < 9; ++k) dotw = fmaf(g[k], w[k], dotw);
  float s2 = 0.f;
  int p = 9;
#pragma unroll
  for (int i = 0; i < 9; ++i)
#pragma unroll
    for (int j = i; j < 9; ++j) {
      float gij = g[p++];
      s2 = fmaf(gij * ((i == j) ? 1.f : 2.f), w[i] * w[j], s2);
    }
  s2 += 2.f * b * dotw + (float)RN * b * b;
  S0[t] = dotw + (float)RN * b;
  S0[64 + t] = s2;
}

// ---------------------------------------------------------------------------
// weight-pack helpers.
// ---------------------------------------------------------------------------
__device__ inline void wpack_one(const float* __restrict__ W, unsigned short* __restrict__ wh,
                                 unsigned short* __restrict__ wl, int t, int lgC, int NK) {
  int k = t >> lgC, c = t & ((1 << lgC) - 1);
  float v = W[t];
  int ct = c >> 4, cl = c & 15, ks = k >> 5, kl = k & 31;
  int dst = ((ct * NK + ks) * 64 + (((kl >> 3) << 4) | cl)) * 8 + (kl & 7);
  unsigned short h = f2bf(v);
  wh[dst] = h; wl[dst] = f2bf(v - bf2f(h));
}
__device__ inline void diffpack_one(const float* __restrict__ W, unsigned short* __restrict__ wh,
                                    unsigned short* __restrict__ wl, int t) {
  int k = t >> 8, cc = t & 255;
  float v = W[k * 256 + cc] - W[(64 + k) * 256 + cc];  // Wtop - Wmid
  int ct = cc >> 4, cl = cc & 15, ks = k >> 5, kl = k & 31;
  int dst = ((ct * 2 + ks) * 64 + (((kl >> 3) << 4) | cl)) * 8 + (kl & 7);
  unsigned short h = f2bf(v);
  wh[dst] = h; wl[dst] = f2bf(v - bf2f(h));
}

// ---------------------------------------------------------------------------
// MEGA kernel (validated r11-r13): knn + fc_bnpack + megaprep.
// ---------------------------------------------------------------------------
__global__ __launch_bounds__(256) void mega_kernel(
    const float4* __restrict__ pack, int* __restrict__ idx,
    const float* __restrict__ data, const float* __restrict__ W_fc,
    const float* __restrict__ b_fc, const float* __restrict__ S0,
    unsigned short* __restrict__ xbh, unsigned short* __restrict__ xbl,
    const float* __restrict__ W1, const float* __restrict__ W4,
    const float* __restrict__ W2, const float* __restrict__ W3,
    const float* __restrict__ W5, const float* __restrict__ W6,
    const float* __restrict__ W10, const float* __restrict__ W11, const float* __restrict__ W12,
    unsigned short* __restrict__ W1mh, unsigned short* __restrict__ W1ml, float4* __restrict__ W1bt,
    unsigned short* __restrict__ W4mh, unsigned short* __restrict__ W4ml,
    unsigned short* __restrict__ W1ph, unsigned short* __restrict__ W1pl,
    unsigned short* __restrict__ W4ph, unsigned short* __restrict__ W4pl,
    unsigned short* __restrict__ W2h, unsigned short* __restrict__ W2l,
    unsigned short* __restrict__ W3h, unsigned short* __restrict__ W3l,
    unsigned short* __restrict__ W5h, unsigned short* __restrict__ W5l,
    unsigned short* __restrict__ W6h, unsigned short* __restrict__ W6l,
    unsigned short* __restrict__ W10h, unsigned short* __restrict__ W10l,
    unsigned short* __restrict__ W11xh, unsigned short* __restrict__ W11xl,
    unsigned short* __restrict__ W12h, unsigned short* __restrict__ W12l) {
  const int blk = blockIdx.x;
  if (blk < 4096) {
    // ------------------------------ KNN ------------------------------
    const int lane = threadIdx.x & 63;
    const int p = blk * 4 + (threadIdx.x >> 6);
    const int b = p >> 12;
    const float4* __restrict__ pb = pack + ((size_t)b << 12);
    const float4 me = pack[p];
    unsigned long long m0 = ~0ull, m1 = ~0ull, m2 = ~0ull, m3 = ~0ull;
#pragma unroll 8
    for (int s = 0; s < 64; ++s) {
      const float4 q = pb[s * 64 + lane];
      float d = me.w + q.w - 2.0f * fmaf(me.x, q.x, fmaf(me.y, q.y, me.z * q.z));
      unsigned ub = __float_as_uint(d);
      ub = (ub & 0x80000000u) ? ~ub : (ub | 0x80000000u);
      unsigned long long k = ((unsigned long long)ub << 12) | (unsigned)(s * 64 + lane);
      if (k < m3) {
        bool l0 = k < m0;  unsigned long long t0 = l0 ? m0 : k;  m0 = l0 ? k : m0;
        bool l1 = t0 < m1; unsigned long long t1 = l1 ? m1 : t0; m1 = l1 ? t0 : m1;
        bool l2 = t1 < m2; unsigned long long t2 = l2 ? m2 : t1; m2 = l2 ? t1 : m2;
        m3 = (t2 < m3) ? t2 : m3;
      }
    }
    for (int pass = 0; pass < 16; ++pass) {
      unsigned d0 = (unsigned)(m0 >> 12);
      unsigned w32 = d0;
#pragma unroll
      for (int mv = 1; mv < 64; mv <<= 1) {
        unsigned o = __shfl_xor(w32, mv);
        w32 = (o < w32) ? o : w32;
      }
      unsigned long long ball = __ballot(d0 == w32);
      unsigned widx;
      if (__popcll(ball) == 1) {
        widx = __shfl((unsigned)(m0 & 0xFFFull), (int)(__ffsll((long long)ball) - 1));
      } else {
        unsigned cand = (d0 == w32) ? (unsigned)(m0 & 0xFFFull) : 0xFFFFFFFFu;
#pragma unroll
        for (int mv = 1; mv < 64; mv <<= 1) {
          unsigned o = __shfl_xor(cand, mv);
          cand = (o < cand) ? o : cand;
        }
        widx = cand;
      }
      const unsigned long long w = ((unsigned long long)w32 << 12) | widx;
      if (lane == pass) idx[(p << 4) + pass] = (int)widx;
      if (m0 == w) { m0 = m1; m1 = m2; m2 = m3; m3 = ~0ull; }
      if (pass < 15 && __any(m0 == ~0ull)) {
        if (m0 == ~0ull) {                    // rare: rebuild from global
          m1 = ~0ull; m2 = ~0ull; m3 = ~0ull;
#pragma unroll 8
          for (int s = 0; s < 64; ++s) {
            const float4 q = pb[s * 64 + lane];
            float d = me.w + q.w - 2.0f * fmaf(me.x, q.x, fmaf(me.y, q.y, me.z * q.z));
            unsigned ub = __float_as_uint(d);
            ub = (ub & 0x80000000u) ? ~ub : (ub | 0x80000000u);
            unsigned long long k = ((unsigned long long)ub << 12) | (unsigned)(s * 64 + lane);
            k = (k > w) ? k : ~0ull;          // exclude consumed
            if (k < m3) {
              bool l0 = k < m0;  unsigned long long t0 = l0 ? m0 : k;  m0 = l0 ? k : m0;
              bool l1 = t0 < m1; unsigned long long t1 = l1 ? m1 : t0; m1 = l1 ? t0 : m1;
              bool l2 = t1 < m2; unsigned long long t2 = l2 ? m2 : t1; m2 = l2 ? t1 : m2;
              m3 = (t2 < m3) ? t2 : m3;
            }
          }
        }
      }
    }
  } else if (blk < 8192) {
    // --------------------------- fc + BN + pack ---------------------------
    const int t = (blk - 4096) * 256 + threadIdx.x;   // RN*64
    const int r = t >> 6, c = t & 63;
    const float* dr = data + (size_t)r * 9;
    float acc = b_fc[c];
#pragma unroll
    for (int k = 0; k < 9; ++k) acc = fmaf(dr[k], W_fc[k * 64 + c], acc);
    const float inv = 1.0f / RN;
    float m = S0[c] * inv;
    float v = fmaxf(S0[64 + c] * inv - m * m, 0.0f);
    float x = fmaxf((acc - m) * rsqrtf(v + EPSBN), 0.0f);
    unsigned short h = f2bf(x);
    xbh[t] = h; xbl[t] = f2bf(x - bf2f(h));
  } else {
    // ------------------------------ megaprep ------------------------------
    const int mb = blk - 8192;
    if (mb < 64) {
      int t = mb * 256 + threadIdx.x;
      int k = t >> 8, cc = t & 255;
      float w1mid = W1[(64 + k) * 256 + cc];
      unsigned short h1 = f2bf(w1mid);
      W1mh[cc * 64 + k] = h1;
      W1ml[cc * 64 + k] = f2bf(w1mid - bf2f(h1));
      float w4mid = W4[(64 + k) * 256 + cc];
      unsigned short h4 = f2bf(w4mid);
      W4mh[cc * 64 + k] = h4;
      W4ml[cc * 64 + k] = f2bf(w4mid - bf2f(h4));
      if (t < 256) W1bt[t] = make_float4(W1[128 * 256 + t], W1[129 * 256 + t], W1[130 * 256 + t], 0.f);
    } else if (mb < 128) {
      diffpack_one(W1, W1ph, W1pl, (mb - 64) * 256 + threadIdx.x);
    } else if (mb < 192) {
      diffpack_one(W4, W4ph, W4pl, (mb - 128) * 256 + threadIdx.x);
    } else if (mb < 256) {
      wpack_one(W2, W2h, W2l, (mb - 192) * 256 + threadIdx.x, 6, 8);
    } else if (mb < 272) {
      wpack_one(W3, W3h, W3l, (mb - 256) * 256 + threadIdx.x, 6, 2);
    } else if (mb < 336) {
      wpack_one(W5, W5h, W5l, (mb - 272) * 256 + threadIdx.x, 6, 8);
    } else if (mb < 352) {
      wpack_one(W6, W6h, W6l, (mb - 336) * 256 + threadIdx.x, 6, 2);
    } else if (mb < 864) {
      wpack_one(W10, W10h, W10l, (mb - 352) * 256 + threadIdx.x, 10, 4);
    } else if (mb < 1120) {
      wpack_one(W11 + 1024 * 512, W11xh, W11xl, (mb - 864) * 256 + threadIdx.x, 9, 4);
    } else {
      wpack_one(W12, W12h, W12l, (mb - 1120) * 256 + threadIdx.x, 8, 16);
    }
  }
}

// [x1|bn(x2)] -> fragment-major hi/lo pack (K=128) (validated r10-r13).
__global__ void pack_x12_kernel(const float* __restrict__ x1, const float* __restrict__ x2,
                                const float* __restrict__ S6,
                                unsigned short* __restrict__ ph, unsigned short* __restrict__ pl) {
  int t = blockIdx.x * 256 + threadIdx.x;   // RN*128
  int r = t >> 7, k = t & 127;
  float v;
  if (k < 64) {
    v = x1[(size_t)r * 64 + k];
  } else {
    int c = k - 64;
    const float inv = 1.0f / RN;
    float m = S6[c] * inv;
    float var = fmaxf(S6[64 + c] * inv - m * m, 0.f);
    v = fmaxf((x2[(size_t)r * 64 + c] - m) * rsqrtf(var + EPSBN), 0.f);
  }
  int rt = r >> 4, rl = r & 15, ks = k >> 5, kl = k & 31;
  int dst = ((rt * 4 + ks) * 64 + (((kl >> 3) << 4) | rl)) * 8 + (kl & 7);
  unsigned short h = f2bf(v);
  ph[dst] = h; pl[dst] = f2bf(v - bf2f(h));
}

// BN+ReLU on h11 (C=512) fused with fragment-major hi/lo pack
__global__ void bn_pack_kernel(const float* __restrict__ buf, const float* __restrict__ stats,
                               unsigned short* __restrict__ ph, unsigned short* __restrict__ pl) {
  int t = blockIdx.x * 256 + threadIdx.x;   // RN*512
  int c = t & 511, r = t >> 9;
  const float inv = 1.0f / RN;
  float m = stats[c] * inv;
  float v = fmaxf(stats[512 + c] * inv - m * m, 0.0f);
  float x = fmaxf((buf[t] - m) * rsqrtf(v + EPSBN), 0.0f);
  int rt = r >> 4, rl = r & 15, ks = c >> 5, kl = c & 31;
  int dst = ((rt * 16 + ks) * 64 + (((kl >> 3) << 4) | rl)) * 8 + (kl & 7);
  unsigned short h = f2bf(x);
  ph[dst] = h; pl[dst] = f2bf(x - bf2f(h));
}

// BN+ReLU in place (C=64) fused with row-major hi/lo write (x1v)
__global__ void bn_normpack_kernel(float* __restrict__ buf, const float* __restrict__ stats,
                                   unsigned short* __restrict__ hi, unsigned short* __restrict__ lo) {
  int t = blockIdx.x * 256 + threadIdx.x;   // RN*64
  int c = t & 63;
  const float inv = 1.0f / RN;
  float m = stats[c] * inv;
  float v = fmaxf(stats[64 + c] * inv - m * m, 0.0f);
  float x = fmaxf((buf[t] - m) * rsqrtf(v + EPSBN), 0.0f);
  buf[t] = x;
  unsigned short h = f2bf(x);
  hi[t] = h; lo[t] = f2bf(x - bf2f(h));
}

// ---------------------------------------------------------------------------
// Edge conv via MFMA with in-kernel basemat (r14): base tile in LDS
// (wave-private, no barriers); NO launch_bounds minimum (r13's forced bound
// caused catastrophic scratch spill); A-fragment prefetch dropped (only the
// 1-reg jn index prefetch) so natural VGPR ~100-110 -> 4 waves/SIMD, no spill.
// Deferred-stats epilogue (r10).
// ---------------------------------------------------------------------------
template <bool HAS_PTS>
__global__ __launch_bounds__(256) void edge_mfma_kernel(
    const unsigned short* __restrict__ Xh, const unsigned short* __restrict__ Xl,
    const int* __restrict__ idx,
    const float4* __restrict__ pack,
    const unsigned short* __restrict__ Wmh, const unsigned short* __restrict__ Wml,
    const unsigned short* __restrict__ Wph, const unsigned short* __restrict__ Wpl,
    const float4* __restrict__ Wbt,
    float* __restrict__ out, float* __restrict__ stats) {
  __shared__ float lds_base[4][16][64];   // [wave][point][col-local]  16 KB
  const int wave = threadIdx.x >> 6;
  const int lane = threadIdx.x & 63;
  const int pg   = blockIdx.x;
  const int c0   = wave << 6;
  const int cl   = lane & 15;
  const int kg   = (lane >> 4) << 3;
  const int bat  = pg >> 8;
  const int pbase = bat << 12;
  const int ib   = pg << 8;

  short8 bh[4][2], blo[4][2];
#pragma unroll
  for (int q = 0; q < 4; ++q) {
    const unsigned short* wp = Wmh + (size_t)(c0 + q * 16 + cl) * 64 + kg;
    bh[q][0] = *(const short8*)wp; bh[q][1] = *(const short8*)(wp + 32);
    const unsigned short* wq = Wml + (size_t)(c0 + q * 16 + cl) * 64 + kg;
    blo[q][0] = *(const short8*)wq; blo[q][1] = *(const short8*)(wq + 32);
  }
  float4 wb[4];
  if (HAS_PTS) {
#pragma unroll
    for (int q = 0; q < 4; ++q) wb[q] = Wbt[c0 + q * 16 + cl];
  }

  // ---- in-kernel basemat -> LDS (registers freed after this block) ----
  {
    const size_t xoff = ((size_t)((pg << 4) + cl)) * 64 + kg;   // row = own point
    short8 xa0h = *(const short8*)(Xh + xoff);
    short8 xa1h = *(const short8*)(Xh + xoff + 32);
    short8 xa0l = *(const short8*)(Xl + xoff);
    short8 xa1l = *(const short8*)(Xl + xoff + 32);
#pragma unroll
    for (int q = 0; q < 4; ++q) {
      f32x4 base = {0.f, 0.f, 0.f, 0.f};
      const int ct = wave * 4 + q;
      const size_t w0 = (((size_t)ct * 2 + 0) * 64 + lane) * 8;
      const size_t w1 = (((size_t)ct * 2 + 1) * 64 + lane) * 8;
      short8 p0h = *(const short8*)(Wph + w0);
      short8 p0l = *(const short8*)(Wpl + w0);
      short8 p1h = *(const short8*)(Wph + w1);
      short8 p1l = *(const short8*)(Wpl + w1);
      base = __builtin_amdgcn_mfma_f32_16x16x32_bf16(xa0l, p0h, base, 0, 0, 0);
      base = __builtin_amdgcn_mfma_f32_16x16x32_bf16(xa0h, p0l, base, 0, 0, 0);
      base = __builtin_amdgcn_mfma_f32_16x16x32_bf16(xa0h, p0h, base, 0, 0, 0);
      base = __builtin_amdgcn_mfma_f32_16x16x32_bf16(xa1l, p1h, base, 0, 0, 0);
      base = __builtin_amdgcn_mfma_f32_16x16x32_bf16(xa1h, p1l, base, 0, 0, 0);
      base = __builtin_amdgcn_mfma_f32_16x16x32_bf16(xa1h, p1h, base, 0, 0, 0);
#pragma unroll
      for (int i = 0; i < 4; ++i)
        lds_base[wave][((lane >> 4) << 2) + i][q * 16 + cl] = base[i];
    }
  }

  float P1[4] = {0.f, 0.f, 0.f, 0.f}, P2[4] = {0.f, 0.f, 0.f, 0.f};
  float PCx[4] = {0.f, 0.f, 0.f, 0.f};
  float PB1[4] = {0.f, 0.f, 0.f, 0.f}, PB2[4] = {0.f, 0.f, 0.f, 0.f};

  int jn = idx[ib + cl];                    // j for point 0
  for (int pp = 0; pp < 16; ++pp) {
    const int p = (pg << 4) | pp;
    const int j = jn;
    if (pp < 15) jn = idx[ib + ((pp + 1) << 4) + cl];
    const size_t ro = ((size_t)(pbase | j) << 6) + kg;
    short8 a0h = *(const short8*)(Xh + ro);
    short8 a1h = *(const short8*)(Xh + ro + 32);
    short8 a0l = *(const short8*)(Xl + ro);
    short8 a1l = *(const short8*)(Xl + ro + 32);
    float dx0, dy0, dz0, dx1, dy1, dz1, dx2, dy2, dz2, dx3, dy3, dz3;
    if (HAS_PTS) {
      const int4 j4 = *(const int4*)(idx + (p << 4) + ((lane >> 4) << 2));
      const float4 pc = pack[p];
      const float4 q0 = pack[pbase | j4.x];
      const float4 q1 = pack[pbase | j4.y];
      const float4 q2 = pack[pbase | j4.z];
      const float4 q3 = pack[pbase | j4.w];
      dx0 = q0.x - pc.x; dy0 = q0.y - pc.y; dz0 = q0.z - pc.z;
      dx1 = q1.x - pc.x; dy1 = q1.y - pc.y; dz1 = q1.z - pc.z;
      dx2 = q2.x - pc.x; dy2 = q2.y - pc.y; dz2 = q2.z - pc.z;
      dx3 = q3.x - pc.x; dy3 = q3.y - pc.y; dz3 = q3.z - pc.z;
    }
    f32x4 acc[4];
#pragma unroll
    for (int q = 0; q < 4; ++q) {
      acc[q][0] = 0.f; acc[q][1] = 0.f; acc[q][2] = 0.f; acc[q][3] = 0.f;
    }
#pragma unroll
    for (int q = 0; q < 4; ++q) {
      acc[q] = __builtin_amdgcn_mfma_f32_16x16x32_bf16(a0l, bh[q][0], acc[q], 0, 0, 0);
      acc[q] = __builtin_amdgcn_mfma_f32_16x16x32_bf16(a1l, bh[q][1], acc[q], 0, 0, 0);
      acc[q] = __builtin_amdgcn_mfma_f32_16x16x32_bf16(a0h, blo[q][0], acc[q], 0, 0, 0);
      acc[q] = __builtin_amdgcn_mfma_f32_16x16x32_bf16(a1h, blo[q][1], acc[q], 0, 0, 0);
      acc[q] = __builtin_amdgcn_mfma_f32_16x16x32_bf16(a0h, bh[q][0], acc[q], 0, 0, 0);
      acc[q] = __builtin_amdgcn_mfma_f32_16x16x32_bf16(a1h, bh[q][1], acc[q], 0, 0, 0);
    }
    if (HAS_PTS) {
#pragma unroll
      for (int q = 0; q < 4; ++q) {
        acc[q][0] += dx0 * wb[q].x + dy0 * wb[q].y + dz0 * wb[q].z;
        acc[q][1] += dx1 * wb[q].x + dy1 * wb[q].y + dz1 * wb[q].z;
        acc[q][2] += dx2 * wb[q].x + dy2 * wb[q].y + dz2 * wb[q].z;
        acc[q][3] += dx3 * wb[q].x + dy3 * wb[q].y + dz3 * wb[q].z;
      }
    }
#pragma unroll
    for (int q = 0; q < 4; ++q) {
      float s1p = acc[q][0] + acc[q][1] + acc[q][2] + acc[q][3];
      float s2p = acc[q][0] * acc[q][0] + acc[q][1] * acc[q][1]
                + acc[q][2] * acc[q][2] + acc[q][3] * acc[q][3];
      float mx = fmaxf(fmaxf(acc[q][0], acc[q][1]), fmaxf(acc[q][2], acc[q][3]));
      mx = fmaxf(mx, __shfl_xor(mx, 16));
      mx = fmaxf(mx, __shfl_xor(mx, 32));
      float bb = lds_base[wave][pp][q * 16 + cl];
      if (lane < 16) out[(size_t)p * 256 + c0 + q * 16 + cl] = mx + bb;
      P1[q] += s1p;
      P2[q] += s2p;
      PCx[q] = fmaf(bb, s1p, PCx[q]);
      PB1[q] += bb;
      PB2[q] = fmaf(bb, bb, PB2[q]);
    }
  }
#pragma unroll
  for (int q = 0; q < 4; ++q) {
    float p1 = P1[q]; p1 += __shfl_xor(p1, 16); p1 += __shfl_xor(p1, 32);
    float p2 = P2[q]; p2 += __shfl_xor(p2, 16); p2 += __shfl_xor(p2, 32);
    float pc = PCx[q]; pc += __shfl_xor(pc, 16); pc += __shfl_xor(pc, 32);
    if (lane < 16) {
      atomicAdd(&stats[c0 + q * 16 + lane], p1 + 16.f * PB1[q]);
      atomicAdd(&stats[256 + c0 + q * 16 + lane], p2 + 2.f * pc + 16.f * PB2[q]);
    }
  }
}

// ---------------------------------------------------------------------------
// agg_pack (validated r10-r13): bn_relu(max over 16 nb) -> packed hi/lo.
// ---------------------------------------------------------------------------
template <int LGC>
__global__ __launch_bounds__(256) void agg_pack_kernel(
    const float* __restrict__ X, const int* __restrict__ idx,
    const float* __restrict__ stats, float inv_cnt,
    unsigned short* __restrict__ ph, unsigned short* __restrict__ pl) {
  const int C = 1 << LGC;
  const int xcd = blockIdx.x & 7, bat = xcd >> 1;
  const int j = ((blockIdx.x >> 3) << 1) | (xcd & 1);
  const int rows_per_block = 256 >> (LGC - 2);
  const int r = bat * 4096 + j * rows_per_block + (threadIdx.x >> (LGC - 2));
  const int cq = threadIdx.x & ((C >> 2) - 1);
  const int base = bat << 12;
  const int* ip = idx + (size_t)r * KSN;
  float4 mx = make_float4(-FLT_MAX, -FLT_MAX, -FLT_MAX, -FLT_MAX);
#pragma unroll
  for (int k = 0; k < KSN; ++k) {
    int jj = ip[k];
    const float4 v = *reinterpret_cast<const float4*>(X + (size_t)(base + jj) * C + cq * 4);
    mx.x = fmaxf(mx.x, v.x); mx.y = fmaxf(mx.y, v.y);
    mx.z = fmaxf(mx.z, v.z); mx.w = fmaxf(mx.w, v.w);
  }
  const int c = cq * 4;
  const float4 sa = *reinterpret_cast<const float4*>(stats + c);
  const float4 sb = *reinterpret_cast<const float4*>(stats + C + c);
  float m0 = sa.x * inv_cnt, m1 = sa.y * inv_cnt, m2 = sa.z * inv_cnt, m3 = sa.w * inv_cnt;
  float o0 = fmaxf((mx.x - m0) * rsqrtf(fmaxf(sb.x * inv_cnt - m0 * m0, 0.f) + EPSBN), 0.f);
  float o1 = fmaxf((mx.y - m1) * rsqrtf(fmaxf(sb.y * inv_cnt - m1 * m1, 0.f) + EPSBN), 0.f);
  float o2 = fmaxf((mx.z - m2) * rsqrtf(fmaxf(sb.z * inv_cnt - m2 * m2, 0.f) + EPSBN), 0.f);
  float o3 = fmaxf((mx.w - m3) * rsqrtf(fmaxf(sb.w * inv_cnt - m3 * m3, 0.f) + EPSBN), 0.f);
  short4v H, L;
  H.x = (short)f2bf(o0); L.x = (short)f2bf(o0 - bf2f((unsigned short)H.x));
  H.y = (short)f2bf(o1); L.y = (short)f2bf(o1 - bf2f((unsigned short)H.y));
  H.z = (short)f2bf(o2); L.z = (short)f2bf(o2 - bf2f((unsigned short)H.z));
  H.w = (short)f2bf(o3); L.w = (short)f2bf(o3 - bf2f((unsigned short)H.w));
  const int NK = C >> 5;
  const int rt = r >> 4, rl = r & 15, ks = c >> 5, kl = c & 31;
  const size_t dst = (((size_t)rt * NK + ks) * 64 + (((kl >> 3) << 4) | rl)) * 8 + (kl & 7);
  *(short4v*)(ph + dst) = H;
  *(short4v*)(pl + dst) = L;
}

// ---------------------------------------------------------------------------
// MFMA GEMM (validated r7-r13): wave = 64 rows x 64 cols, acc[4][4].
// ---------------------------------------------------------------------------
template <int AMODE, bool DOMAX, bool BIAS>
__global__ __launch_bounds__(256) void gemm_mfma_kernel(
    const unsigned short* __restrict__ Ah, const unsigned short* __restrict__ Al,
    const unsigned short* __restrict__ Wh, const unsigned short* __restrict__ Wl,
    float* __restrict__ Y, float* __restrict__ pmax, float* __restrict__ stats,
    const float* __restrict__ gbias,
    int K, int C) {
  __shared__ float red1[4][64], red2[4][64], redm[4][64];
  const int wave = threadIdx.x >> 6, lane = threadIdx.x & 63;
  const int rtb = blockIdx.x * 16 + wave * 4;
  const int c0  = blockIdx.y * 64;
  const int ct0 = blockIdx.y * 4;
  const int NK  = K >> 5;
  const int bat = blockIdx.x >> 4;
  f32x4 acc[4][4];
#pragma unroll
  for (int r = 0; r < 4; ++r)
#pragma unroll
    for (int cc = 0; cc < 4; ++cc) {
      acc[r][cc][0] = 0.f; acc[r][cc][1] = 0.f; acc[r][cc][2] = 0.f; acc[r][cc][3] = 0.f;
    }
  const int lhalf = (lane >> 4) << 3;
  for (int ks = 0; ks < NK; ++ks) {
    short8 ah[4], al[4];
    if (AMODE == 1) {
#pragma unroll
      for (int r = 0; r < 4; ++r) {
        const size_t aoff = ((size_t)((rtb + r) * 16 + (lane & 15))) * 64 + ks * 32 + lhalf;
        ah[r] = *(const short8*)(Ah + aoff);
        al[r] = *(const short8*)(Al + aoff);
      }
    } else {
#pragma unroll
      for (int r = 0; r < 4; ++r) {
        const size_t aoff = (((size_t)(rtb + r) * NK + ks) * 64 + lane) * 8;
        ah[r] = *(const short8*)(Ah + aoff);
        al[r] = *(const short8*)(Al + aoff);
      }
    }
#pragma unroll
    for (int cc = 0; cc < 4; ++cc) {
      const size_t woff = (((size_t)(ct0 + cc) * NK + ks) * 64 + lane) * 8;
      short8 bh = *(const short8*)(Wh + woff);
      short8 bl = *(const short8*)(Wl + woff);
#pragma unroll
      for (int r = 0; r < 4; ++r) {
        acc[r][cc] = __builtin_amdgcn_mfma_f32_16x16x32_bf16(al[r], bh, acc[r][cc], 0, 0, 0);
        acc[r][cc] = __builtin_amdgcn_mfma_f32_16x16x32_bf16(ah[r], bl, acc[r][cc], 0, 0, 0);
        acc[r][cc] = __builtin_amdgcn_mfma_f32_16x16x32_bf16(ah[r], bh, acc[r][cc], 0, 0, 0);
      }
    }
  }
#pragma unroll
  for (int cc = 0; cc < 4; ++cc) {
    float bv = 0.f;
    if (BIAS) bv = gbias[(size_t)bat * C + c0 + cc * 16 + (lane & 15)];
    float s1 = 0.f, s2 = 0.f, mm = -FLT_MAX;
#pragma unroll
    for (int r = 0; r < 4; ++r) {
#pragma unroll
      for (int i = 0; i < 4; ++i) {
        float v = acc[r][cc][i] + bv;
        if (!DOMAX)
          Y[(size_t)((rtb + r) * 16 + ((lane >> 4) << 2) + i) * C + c0 + cc * 16 + (lane & 15)] = v;
        s1 += v; s2 = fmaf(v, v, s2); mm = fmaxf(mm, v);
      }
    }
    s1 += __shfl_xor(s1, 16); s1 += __shfl_xor(s1, 32);
    s2 += __shfl_xor(s2, 16); s2 += __shfl_xor(s2, 32);
    mm = fmaxf(mm, __shfl_xor(mm, 16)); mm = fmaxf(mm, __shfl_xor(mm, 32));
    if (lane < 16) {
      red1[wave][cc * 16 + lane] = s1;
      red2[wave][cc * 16 + lane] = s2;
      if (DOMAX) redm[wave][cc * 16 + lane] = mm;
    }
  }
  __syncthreads();
  if (threadIdx.x < 64) {
    const int t = threadIdx.x;
    float a = red1[0][t] + red1[1][t] + red1[2][t] + red1[3][t];
    float b = red2[0][t] + red2[1][t] + red2[2][t] + red2[3][t];
    atomicAdd(&stats[c0 + t], a);
    atomicAdd(&stats[C + c0 + t], b);
    if (DOMAX) {
      float mm = fmaxf(fmaxf(redm[0][t], redm[1][t]), fmaxf(redm[2][t], redm[3][t]));
      pmax[(size_t)blockIdx.x * C + c0 + t] = mm;
    }
  }
}

// ---------------------------------------------------------------------------
// fin_g + gb11 fused (validated r12/r13).
// ---------------------------------------------------------------------------
__global__ __launch_bounds__(256) void fing_gb_kernel(const float* __restrict__ pmax,
                                                      const float* __restrict__ S7,
                                                      const float* __restrict__ W11,
                                                      float* __restrict__ gb) {
  __shared__ float g_lds[1024];
  const int t = threadIdx.x;
  const int b = blockIdx.x >> 1, ch = blockIdx.x & 1;
  const float inv = 1.0f / 16384.0f;
#pragma unroll
  for (int kk = 0; kk < 4; ++kk) {
    int c = kk * 256 + t;
    float m = S7[c] * inv;
    float v = fmaxf(S7[1024 + c] * inv - m * m, 0.0f);
    float rs = rsqrtf(v + EPSBN);
    float mx = -FLT_MAX;
    for (int s = 0; s < 16; ++s) mx = fmaxf(mx, pmax[(size_t)(b * 16 + s) * 1024 + c]);
    g_lds[c] = fmaxf((mx - m) * rs, 0.0f);
  }
  __syncthreads();
  const int c_out = ch * 256 + t;
  float acc = 0.f;
#pragma unroll 8
  for (int k = 0; k < 1024; ++k) acc = fmaf(g_lds[k], W11[(size_t)k * 512 + c_out], acc);
  gb[b * 512 + c_out] = acc;
}

// final13 with fused BN(h12) (validated r10-r13)
__global__ __launch_bounds__(256) void final13_kernel(const float* __restrict__ h,
                                                      const float* __restrict__ S9,
                                                      const float* __restrict__ W,
                                                      float* __restrict__ out) {
  __shared__ float wl[256 * 13];
  __shared__ float ms[256], rs[256];
  const int t = threadIdx.x;
  {
    const float inv = 1.0f / RN;
    float m = S9[t] * inv;
    float v = fmaxf(S9[256 + t] * inv - m * m, 0.0f);
    ms[t] = m; rs[t] = rsqrtf(v + EPSBN);
#pragma unroll
    for (int i = 0; i < 13; ++i) wl[t * 13 + i] = W[t * 13 + i];
  }
  __syncthreads();
  const int r = blockIdx.x * 16 + (t >> 4);
  const int c = t & 15;
  const int ci = (c < 13) ? c : 0;
  const float* hr = h + (size_t)r * 256;
  float acc = 0.0f;
  for (int k = 0; k < 256; ++k) {
    float x = fmaxf((hr[k] - ms[k]) * rs[k], 0.0f);
    acc = fmaf(x, wl[k * 13 + ci], acc);
  }
  if (c < 13) {
    int b = r >> 12, n = r & 4095;
    out[(size_t)b * 13 * NN + (size_t)c * NN + n] = acc;
  }
}

// ---------------------------------------------------------------------------
extern "C" void kernel_launch(void* const* d_in, const int* in_sizes, int n_in,
                              void* d_out, int out_size, void* d_ws, size_t ws_size,
                              hipStream_t stream) {
  (void)in_sizes; (void)n_in; (void)out_size; (void)ws_size;
  const float* data = (const float*)d_in[0];
  const float* W_fc = (const float*)d_in[1];
  const float* b_fc = (const float*)d_in[2];
  const float* W1   = (const float*)d_in[3];
  const float* W2   = (const float*)d_in[4];
  const float* W3   = (const float*)d_in[5];
  const float* W4   = (const float*)d_in[6];
  const float* W5   = (const float*)d_in[7];
  const float* W6   = (const float*)d_in[8];
  const float* W10  = (const float*)d_in[9];
  const float* W11  = (const float*)d_in[10];
  const float* W12  = (const float*)d_in[11];
  const float* W13  = (const float*)d_in[12];
  float* out = (float*)d_out;

  float* ws  = (float*)d_ws;
  int*   idx = (int*)d_ws;
  size_t o = 262144;
  float* x0   = ws + o; o += (size_t)RN * 64;     // dead fp32; hosts x12l overlay
  float* x1v  = ws + o; o += (size_t)RN * 64;
  float* x2v  = ws + o; o += (size_t)RN * 64;
  float* bufA = ws + o; o += (size_t)RN * 256;
  float* bufB = ws + o; o += (size_t)RN * 256;    // hosts h11l overlay
  float* bufC = ws + o; o += (size_t)RN * 64;
  float* pmax = ws + o; o += (size_t)64 * 1024;
  float* h11  = ws + o; o += (size_t)RN * 512;
  float* h12  = ws + o; o += (size_t)RN * 256;
  float* stats = ws + o; o += 8192;
  float4* pack = (float4*)(ws + o); o += (size_t)RN * 4;
  unsigned short* xbh = (unsigned short*)(ws + o); o += (size_t)RN * 32;
  unsigned short* xbl = (unsigned short*)(ws + o); o += (size_t)RN * 32;
  unsigned short* W1mh = (unsigned short*)(ws + o); o += 8192;
  unsigned short* W1ml = (unsigned short*)(ws + o); o += 8192;
  unsigned short* W4mh = (unsigned short*)(ws + o); o += 8192;
  unsigned short* W4ml = (unsigned short*)(ws + o); o += 8192;
  float4* W1bt = (float4*)(ws + o); o += 1024;
  unsigned short* W10h = (unsigned short*)(ws + o); o += 65536;
  unsigned short* W10l = (unsigned short*)(ws + o); o += 65536;
  unsigned short* W11xh = (unsigned short*)(ws + o); o += 32768;
  unsigned short* W11xl = (unsigned short*)(ws + o); o += 32768;
  unsigned short* W12h = (unsigned short*)(ws + o); o += 65536;
  unsigned short* W12l = (unsigned short*)(ws + o); o += 65536;
  float* gb = ws + o; o += 2048;
  unsigned short* W1ph = (unsigned short*)(ws + o); o += 8192;
  unsigned short* W1pl = (unsigned short*)(ws + o); o += 8192;
  unsigned short* W4ph = (unsigned short*)(ws + o); o += 8192;
  unsigned short* W4pl = (unsigned short*)(ws + o); o += 8192;
  unsigned short* W2h  = (unsigned short*)(ws + o); o += 8192;
  unsigned short* W2l  = (unsigned short*)(ws + o); o += 8192;
  unsigned short* W3h  = (unsigned short*)(ws + o); o += 2048;
  unsigned short* W3l  = (unsigned short*)(ws + o); o += 2048;
  unsigned short* W5h  = (unsigned short*)(ws + o); o += 8192;
  unsigned short* W5l  = (unsigned short*)(ws + o); o += 8192;
  unsigned short* W6h  = (unsigned short*)(ws + o); o += 2048;
  unsigned short* W6l  = (unsigned short*)(ws + o); o += 2048;
  float* gpart = ws + o; o += 64 * 54;
  // overlays on dead buffers:
  unsigned short* x12h = (unsigned short*)bufC;
  unsigned short* x12l = (unsigned short*)x0;
  unsigned short* h11h = (unsigned short*)bufA;
  unsigned short* h11l = (unsigned short*)bufB;
  unsigned short* aggh = (unsigned short*)h11;
  unsigned short* aggl = (unsigned short*)h11 + (size_t)RN * 256;

  float* S0 = stats;          // 64 (fc)
  float* S1 = stats + 128;    // 256 (edge1)
  float* S2 = stats + 640;    // 64  (W2)
  float* S3 = stats + 768;    // 64  (W3)
  float* S4 = stats + 896;    // 256 (edge2)
  float* S5 = stats + 1408;   // 64  (W5)
  float* S6 = stats + 1536;   // 64  (W6)
  float* S7 = stats + 1664;   // 1024 (W10)
  float* S8 = stats + 3712;   // 512 (W11)
  float* S9 = stats + 4736;   // 256 (W12)

  hipMemsetAsync(stats, 0, 8192 * sizeof(float), stream);

  prepgram_kernel<<<64, 256, 0, stream>>>(data, pack, gpart);
  fcstats_kernel<<<1, 64, 0, stream>>>(gpart, W_fc, b_fc, S0);

  // MEGA: knn (4096 blocks) + fc_bnpack (4096) + megaprep (1632)
  mega_kernel<<<9824, 256, 0, stream>>>(
      pack, idx, data, W_fc, b_fc, S0, xbh, xbl,
      W1, W4, W2, W3, W5, W6, W10, W11, W12,
      W1mh, W1ml, W1bt, W4mh, W4ml,
      W1ph, W1pl, W4ph, W4pl, W2h, W2l, W3h, W3l, W5h, W5l, W6h, W6l,
      W10h, W10l, W11xh, W11xl, W12h, W12l);

  // edge conv 1 (basemat computed in-kernel, base tile in LDS)
  edge_mfma_kernel<true><<<1024, 256, 0, stream>>>(
      xbh, xbl, idx, pack, W1mh, W1ml, W1ph, W1pl, W1bt, bufA, S1);

  // graph conv 1
  agg_pack_kernel<8><<<4096, 256, 0, stream>>>(bufA, idx, S1, 1.0f / (RN * 16), aggh, aggl);
  gemm_mfma_kernel<0, false, false><<<dim3(64, 1), 256, 0, stream>>>(
      aggh, aggl, W2h, W2l, bufC, nullptr, S2, nullptr, 256, 64);

  // graph conv 2
  agg_pack_kernel<6><<<1024, 256, 0, stream>>>(bufC, idx, S2, 1.0f / RN, aggh, aggl);
  gemm_mfma_kernel<0, false, false><<<dim3(64, 1), 256, 0, stream>>>(
      aggh, aggl, W3h, W3l, x1v, nullptr, S3, nullptr, 64, 64);
  bn_normpack_kernel<<<RN * 64 / 256, 256, 0, stream>>>(x1v, S3, xbh, xbl);

  // edge conv 2 (no pts; basemat in-kernel, base tile in LDS)
  edge_mfma_kernel<false><<<1024, 256, 0, stream>>>(
      xbh, xbl, idx, pack, W4mh, W4ml, W4ph, W4pl, nullptr, bufA, S4);

  // graph conv 3
  agg_pack_kernel<8><<<4096, 256, 0, stream>>>(bufA, idx, S4, 1.0f / (RN * 16), aggh, aggl);
  gemm_mfma_kernel<0, false, false><<<dim3(64, 1), 256, 0, stream>>>(
      aggh, aggl, W5h, W5l, bufC, nullptr, S5, nullptr, 256, 64);

  // graph conv 4 -> x2v raw (+S6); bn fused into pack_x12
  agg_pack_kernel<6><<<1024, 256, 0, stream>>>(bufC, idx, S5, 1.0f / RN, aggh, aggl);
  gemm_mfma_kernel<0, false, false><<<dim3(64, 1), 256, 0, stream>>>(
      aggh, aggl, W6h, W6l, x2v, nullptr, S6, nullptr, 64, 64);

  // pack [x1|bn(x2)]
  pack_x12_kernel<<<RN * 128 / 256, 256, 0, stream>>>(x1v, x2v, S6, x12h, x12l);

  // W10 path
  gemm_mfma_kernel<0, true, false><<<dim3(64, 16), 256, 0, stream>>>(
      x12h, x12l, W10h, W10l, nullptr, pmax, S7, nullptr, 128, 1024);

  // fused fin_g + gb11
  fing_gb_kernel<<<8, 256, 0, stream>>>(pmax, S7, W11, gb);

  // W11: K=128 MFMA gemm + per-batch g-bias
  gemm_mfma_kernel<0, false, true><<<dim3(64, 8), 256, 0, stream>>>(
      x12h, x12l, W11xh, W11xl, h11, nullptr, S8, gb, 128, 512);
  bn_pack_kernel<<<RN * 512 / 256, 256, 0, stream>>>(h11, S8, h11h, h11l);

  // W12 -> h12 raw (+S9); bn fused into final13
  gemm_mfma_kernel<0, false, false><<<dim3(64, 4), 256, 0, stream>>>(
      h11h, h11l, W12h, W12l, h12, nullptr, S9, nullptr, 512, 256);

  final13_kernel<<<RN / 16, 256, 0, stream>>>(h12, S9, W13, out);
}

// Round 15
// 522.793 us; speedup vs baseline: 1.2696x; 1.0440x over previous
//
#include <hip/hip_runtime.h>
#include <hip/hip_bf16.h>
#include <float.h>

static constexpr int BB  = 4;
static constexpr int NN  = 4096;
static constexpr int KSN = 16;
static constexpr int RN  = BB * NN;     // 16384 rows (b,n)
#define EPSBN 1e-5f

typedef __attribute__((ext_vector_type(8))) short short8;
typedef __attribute__((ext_vector_type(4))) short short4v;
typedef __attribute__((ext_vector_type(4))) float f32x4;

__device__ inline unsigned short f2bf(float f) {
  union { float f; unsigned u; } v; v.f = f;
  unsigned r = v.u + 0x7FFF + ((v.u >> 16) & 1);
  return (unsigned short)(r >> 16);
}
__device__ inline float bf2f(unsigned short h) {
  union { unsigned u; float f; } v; v.u = ((unsigned)h) << 16; return v.f;
}

// ---------------------------------------------------------------------------
// prep + gram fused (validated r10-r14).
// ---------------------------------------------------------------------------
__global__ __launch_bounds__(256) void prepgram_kernel(const float* __restrict__ data,
                                                       float4* __restrict__ pack,
                                                       float* __restrict__ partials) {
  const int t = blockIdx.x * 256 + threadIdx.x;   // RN
  const int lane = threadIdx.x & 63, wave = threadIdx.x >> 6;
  __shared__ float red[4][54];
  float d[9];
#pragma unroll
  for (int k = 0; k < 9; ++k) d[k] = data[(size_t)t * 9 + k];
  pack[t] = make_float4(d[0], d[1], d[2], fmaf(d[2], d[2], fmaf(d[1], d[1], d[0] * d[0])));
  int p = 0;
#pragma unroll
  for (int i = 0; i < 9; ++i) {
    float v = d[i];
#pragma unroll
    for (int mv = 1; mv < 64; mv <<= 1) v += __shfl_xor(v, mv);
    if (lane == 0) red[wave][p] = v;
    ++p;
  }
#pragma unroll
  for (int i = 0; i < 9; ++i)
#pragma unroll
    for (int j = i; j < 9; ++j) {
      float v = d[i] * d[j];
#pragma unroll
      for (int mv = 1; mv < 64; mv <<= 1) v += __shfl_xor(v, mv);
      if (lane == 0) red[wave][p] = v;
      ++p;
    }
  __syncthreads();
  if (threadIdx.x < 54)
    partials[blockIdx.x * 54 + threadIdx.x] =
        red[0][threadIdx.x] + red[1][threadIdx.x] + red[2][threadIdx.x] + red[3][threadIdx.x];
}

__global__ void fcstats_kernel(const float* __restrict__ partials,
                               const float* __restrict__ W, const float* __restrict__ bias,
                               float* __restrict__ S0) {
  __shared__ float g[54];
  const int t = threadIdx.x;   // 64 threads
  if (t < 54) {
    float s = 0.f;
    for (int b = 0; b < 64; ++b) s += partials[b * 54 + t];
    g[t] = s;
  }
  __syncthreads();
  float w[9];
#pragma unroll
  for (int k = 0; k < 9; ++k) w[k] = W[k * 64 + t];
  float b = bias[t];
  float dotw = 0.f;
#pragma unroll
  for (int k = 0; k < 9; ++k) dotw = fmaf(g[k], w[k], dotw);
  float s2 = 0.f;
  int p = 9;
#pragma unroll
  for (int i = 0; i < 9; ++i)
#pragma unroll
    for (int j = i; j < 9; ++j) {
      float gij = g[p++];
      s2 = fmaf(gij * ((i == j) ? 1.f : 2.f), w[i] * w[j], s2);
    }
  s2 += 2.f * b * dotw + (float)RN * b * b;
  S0[t] = dotw + (float)RN * b;
  S0[64 + t] = s2;
}

// ---------------------------------------------------------------------------
// weight-pack helpers.
// ---------------------------------------------------------------------------
__device__ inline void wpack_one(const float* __restrict__ W, unsigned short* __restrict__ wh,
                                 unsigned short* __restrict__ wl, int t, int lgC, int NK) {
  int k = t >> lgC, c = t & ((1 << lgC) - 1);
  float v = W[t];
  int ct = c >> 4, cl = c & 15, ks = k >> 5, kl = k & 31;
  int dst = ((ct * NK + ks) * 64 + (((kl >> 3) << 4) | cl)) * 8 + (kl & 7);
  unsigned short h = f2bf(v);
  wh[dst] = h; wl[dst] = f2bf(v - bf2f(h));
}
__device__ inline void diffpack_one(const float* __restrict__ W, unsigned short* __restrict__ wh,
                                    unsigned short* __restrict__ wl, int t) {
  int k = t >> 8, cc = t & 255;
  float v = W[k * 256 + cc] - W[(64 + k) * 256 + cc];  // Wtop - Wmid
  int ct = cc >> 4, cl = cc & 15, ks = k >> 5, kl = k & 31;
  int dst = ((ct * 2 + ks) * 64 + (((kl >> 3) << 4) | cl)) * 8 + (kl & 7);
  unsigned short h = f2bf(v);
  wh[dst] = h; wl[dst] = f2bf(v - bf2f(h));
}

// ---------------------------------------------------------------------------
// MEGA kernel (validated r11-r14): knn + fc_bnpack + megaprep.
// ---------------------------------------------------------------------------
__global__ __launch_bounds__(256) void mega_kernel(
    const float4* __restrict__ pack, int* __restrict__ idx,
    const float* __restrict__ data, const float* __restrict__ W_fc,
    const float* __restrict__ b_fc, const float* __restrict__ S0,
    unsigned short* __restrict__ xbh, unsigned short* __restrict__ xbl,
    const float* __restrict__ W1, const float* __restrict__ W4,
    const float* __restrict__ W2, const float* __restrict__ W3,
    const float* __restrict__ W5, const float* __restrict__ W6,
    const float* __restrict__ W10, const float* __restrict__ W11, const float* __restrict__ W12,
    unsigned short* __restrict__ W1mh, unsigned short* __restrict__ W1ml, float4* __restrict__ W1bt,
    unsigned short* __restrict__ W4mh, unsigned short* __restrict__ W4ml,
    unsigned short* __restrict__ W1ph, unsigned short* __restrict__ W1pl,
    unsigned short* __restrict__ W4ph, unsigned short* __restrict__ W4pl,
    unsigned short* __restrict__ W2h, unsigned short* __restrict__ W2l,
    unsigned short* __restrict__ W3h, unsigned short* __restrict__ W3l,
    unsigned short* __restrict__ W5h, unsigned short* __restrict__ W5l,
    unsigned short* __restrict__ W6h, unsigned short* __restrict__ W6l,
    unsigned short* __restrict__ W10h, unsigned short* __restrict__ W10l,
    unsigned short* __restrict__ W11xh, unsigned short* __restrict__ W11xl,
    unsigned short* __restrict__ W12h, unsigned short* __restrict__ W12l) {
  const int blk = blockIdx.x;
  if (blk < 4096) {
    // ------------------------------ KNN ------------------------------
    const int lane = threadIdx.x & 63;
    const int p = blk * 4 + (threadIdx.x >> 6);
    const int b = p >> 12;
    const float4* __restrict__ pb = pack + ((size_t)b << 12);
    const float4 me = pack[p];
    unsigned long long m0 = ~0ull, m1 = ~0ull, m2 = ~0ull, m3 = ~0ull;
#pragma unroll 8
    for (int s = 0; s < 64; ++s) {
      const float4 q = pb[s * 64 + lane];
      float d = me.w + q.w - 2.0f * fmaf(me.x, q.x, fmaf(me.y, q.y, me.z * q.z));
      unsigned ub = __float_as_uint(d);
      ub = (ub & 0x80000000u) ? ~ub : (ub | 0x80000000u);
      unsigned long long k = ((unsigned long long)ub << 12) | (unsigned)(s * 64 + lane);
      if (k < m3) {
        bool l0 = k < m0;  unsigned long long t0 = l0 ? m0 : k;  m0 = l0 ? k : m0;
        bool l1 = t0 < m1; unsigned long long t1 = l1 ? m1 : t0; m1 = l1 ? t0 : m1;
        bool l2 = t1 < m2; unsigned long long t2 = l2 ? m2 : t1; m2 = l2 ? t1 : m2;
        m3 = (t2 < m3) ? t2 : m3;
      }
    }
    for (int pass = 0; pass < 16; ++pass) {
      unsigned d0 = (unsigned)(m0 >> 12);
      unsigned w32 = d0;
#pragma unroll
      for (int mv = 1; mv < 64; mv <<= 1) {
        unsigned o = __shfl_xor(w32, mv);
        w32 = (o < w32) ? o : w32;
      }
      unsigned long long ball = __ballot(d0 == w32);
      unsigned widx;
      if (__popcll(ball) == 1) {
        widx = __shfl((unsigned)(m0 & 0xFFFull), (int)(__ffsll((long long)ball) - 1));
      } else {
        unsigned cand = (d0 == w32) ? (unsigned)(m0 & 0xFFFull) : 0xFFFFFFFFu;
#pragma unroll
        for (int mv = 1; mv < 64; mv <<= 1) {
          unsigned o = __shfl_xor(cand, mv);
          cand = (o < cand) ? o : cand;
        }
        widx = cand;
      }
      const unsigned long long w = ((unsigned long long)w32 << 12) | widx;
      if (lane == pass) idx[(p << 4) + pass] = (int)widx;
      if (m0 == w) { m0 = m1; m1 = m2; m2 = m3; m3 = ~0ull; }
      if (pass < 15 && __any(m0 == ~0ull)) {
        if (m0 == ~0ull) {                    // rare: rebuild from global
          m1 = ~0ull; m2 = ~0ull; m3 = ~0ull;
#pragma unroll 8
          for (int s = 0; s < 64; ++s) {
            const float4 q = pb[s * 64 + lane];
            float d = me.w + q.w - 2.0f * fmaf(me.x, q.x, fmaf(me.y, q.y, me.z * q.z));
            unsigned ub = __float_as_uint(d);
            ub = (ub & 0x80000000u) ? ~ub : (ub | 0x80000000u);
            unsigned long long k = ((unsigned long long)ub << 12) | (unsigned)(s * 64 + lane);
            k = (k > w) ? k : ~0ull;          // exclude consumed
            if (k < m3) {
              bool l0 = k < m0;  unsigned long long t0 = l0 ? m0 : k;  m0 = l0 ? k : m0;
              bool l1 = t0 < m1; unsigned long long t1 = l1 ? m1 : t0; m1 = l1 ? t0 : m1;
              bool l2 = t1 < m2; unsigned long long t2 = l2 ? m2 : t1; m2 = l2 ? t1 : m2;
              m3 = (t2 < m3) ? t2 : m3;
            }
          }
        }
      }
    }
  } else if (blk < 8192) {
    // --------------------------- fc + BN + pack ---------------------------
    const int t = (blk - 4096) * 256 + threadIdx.x;   // RN*64
    const int r = t >> 6, c = t & 63;
    const float* dr = data + (size_t)r * 9;
    float acc = b_fc[c];
#pragma unroll
    for (int k = 0; k < 9; ++k) acc = fmaf(dr[k], W_fc[k * 64 + c], acc);
    const float inv = 1.0f / RN;
    float m = S0[c] * inv;
    float v = fmaxf(S0[64 + c] * inv - m * m, 0.0f);
    float x = fmaxf((acc - m) * rsqrtf(v + EPSBN), 0.0f);
    unsigned short h = f2bf(x);
    xbh[t] = h; xbl[t] = f2bf(x - bf2f(h));
  } else {
    // ------------------------------ megaprep ------------------------------
    const int mb = blk - 8192;
    if (mb < 64) {
      int t = mb * 256 + threadIdx.x;
      int k = t >> 8, cc = t & 255;
      float w1mid = W1[(64 + k) * 256 + cc];
      unsigned short h1 = f2bf(w1mid);
      W1mh[cc * 64 + k] = h1;
      W1ml[cc * 64 + k] = f2bf(w1mid - bf2f(h1));
      float w4mid = W4[(64 + k) * 256 + cc];
      unsigned short h4 = f2bf(w4mid);
      W4mh[cc * 64 + k] = h4;
      W4ml[cc * 64 + k] = f2bf(w4mid - bf2f(h4));
      if (t < 256) W1bt[t] = make_float4(W1[128 * 256 + t], W1[129 * 256 + t], W1[130 * 256 + t], 0.f);
    } else if (mb < 128) {
      diffpack_one(W1, W1ph, W1pl, (mb - 64) * 256 + threadIdx.x);
    } else if (mb < 192) {
      diffpack_one(W4, W4ph, W4pl, (mb - 128) * 256 + threadIdx.x);
    } else if (mb < 256) {
      wpack_one(W2, W2h, W2l, (mb - 192) * 256 + threadIdx.x, 6, 8);
    } else if (mb < 272) {
      wpack_one(W3, W3h, W3l, (mb - 256) * 256 + threadIdx.x, 6, 2);
    } else if (mb < 336) {
      wpack_one(W5, W5h, W5l, (mb - 272) * 256 + threadIdx.x, 6, 8);
    } else if (mb < 352) {
      wpack_one(W6, W6h, W6l, (mb - 336) * 256 + threadIdx.x, 6, 2);
    } else if (mb < 864) {
      wpack_one(W10, W10h, W10l, (mb - 352) * 256 + threadIdx.x, 10, 4);
    } else if (mb < 1120) {
      wpack_one(W11 + 1024 * 512, W11xh, W11xl, (mb - 864) * 256 + threadIdx.x, 9, 4);
    } else {
      wpack_one(W12, W12h, W12l, (mb - 1120) * 256 + threadIdx.x, 8, 16);
    }
  }
}

// [x1|bn(x2)] -> fragment-major hi/lo pack (K=128) (validated r10-r14).
__global__ void pack_x12_kernel(const float* __restrict__ x1, const float* __restrict__ x2,
                                const float* __restrict__ S6,
                                unsigned short* __restrict__ ph, unsigned short* __restrict__ pl) {
  int t = blockIdx.x * 256 + threadIdx.x;   // RN*128
  int r = t >> 7, k = t & 127;
  float v;
  if (k < 64) {
    v = x1[(size_t)r * 64 + k];
  } else {
    int c = k - 64;
    const float inv = 1.0f / RN;
    float m = S6[c] * inv;
    float var = fmaxf(S6[64 + c] * inv - m * m, 0.f);
    v = fmaxf((x2[(size_t)r * 64 + c] - m) * rsqrtf(var + EPSBN), 0.f);
  }
  int rt = r >> 4, rl = r & 15, ks = k >> 5, kl = k & 31;
  int dst = ((rt * 4 + ks) * 64 + (((kl >> 3) << 4) | rl)) * 8 + (kl & 7);
  unsigned short h = f2bf(v);
  ph[dst] = h; pl[dst] = f2bf(v - bf2f(h));
}

// BN+ReLU on h11 (C=512) fused with fragment-major hi/lo pack
__global__ void bn_pack_kernel(const float* __restrict__ buf, const float* __restrict__ stats,
                               unsigned short* __restrict__ ph, unsigned short* __restrict__ pl) {
  int t = blockIdx.x * 256 + threadIdx.x;   // RN*512
  int c = t & 511, r = t >> 9;
  const float inv = 1.0f / RN;
  float m = stats[c] * inv;
  float v = fmaxf(stats[512 + c] * inv - m * m, 0.0f);
  float x = fmaxf((buf[t] - m) * rsqrtf(v + EPSBN), 0.0f);
  int rt = r >> 4, rl = r & 15, ks = c >> 5, kl = c & 31;
  int dst = ((rt * 16 + ks) * 64 + (((kl >> 3) << 4) | rl)) * 8 + (kl & 7);
  unsigned short h = f2bf(x);
  ph[dst] = h; pl[dst] = f2bf(x - bf2f(h));
}

// BN+ReLU in place (C=64) fused with row-major hi/lo write (x1v)
__global__ void bn_normpack_kernel(float* __restrict__ buf, const float* __restrict__ stats,
                                   unsigned short* __restrict__ hi, unsigned short* __restrict__ lo) {
  int t = blockIdx.x * 256 + threadIdx.x;   // RN*64
  int c = t & 63;
  const float inv = 1.0f / RN;
  float m = stats[c] * inv;
  float v = fmaxf(stats[64 + c] * inv - m * m, 0.0f);
  float x = fmaxf((buf[t] - m) * rsqrtf(v + EPSBN), 0.0f);
  buf[t] = x;
  unsigned short h = f2bf(x);
  hi[t] = h; lo[t] = f2bf(x - bf2f(h));
}

// ---------------------------------------------------------------------------
// Edge conv via MFMA (r15): LDS base tile (r14, -16 VGPR) + A-fragment
// prefetch one point ahead (r12 ILP). Natural allocation (~116 VGPR,
// no launch_bounds minimum -> no spill). Deferred-stats epilogue (r10).
// ---------------------------------------------------------------------------
template <bool HAS_PTS>
__global__ __launch_bounds__(256) void edge_mfma_kernel(
    const unsigned short* __restrict__ Xh, const unsigned short* __restrict__ Xl,
    const int* __restrict__ idx,
    const float4* __restrict__ pack,
    const unsigned short* __restrict__ Wmh, const unsigned short* __restrict__ Wml,
    const unsigned short* __restrict__ Wph, const unsigned short* __restrict__ Wpl,
    const float4* __restrict__ Wbt,
    float* __restrict__ out, float* __restrict__ stats) {
  __shared__ float lds_base[4][16][64];   // [wave][point][col-local]  16 KB
  const int wave = threadIdx.x >> 6;
  const int lane = threadIdx.x & 63;
  const int pg   = blockIdx.x;
  const int c0   = wave << 6;
  const int cl   = lane & 15;
  const int kg   = (lane >> 4) << 3;
  const int bat  = pg >> 8;
  const int pbase = bat << 12;
  const int ib   = pg << 8;

  short8 bh[4][2], blo[4][2];
#pragma unroll
  for (int q = 0; q < 4; ++q) {
    const unsigned short* wp = Wmh + (size_t)(c0 + q * 16 + cl) * 64 + kg;
    bh[q][0] = *(const short8*)wp; bh[q][1] = *(const short8*)(wp + 32);
    const unsigned short* wq = Wml + (size_t)(c0 + q * 16 + cl) * 64 + kg;
    blo[q][0] = *(const short8*)wq; blo[q][1] = *(const short8*)(wq + 32);
  }
  float4 wb[4];
  if (HAS_PTS) {
#pragma unroll
    for (int q = 0; q < 4; ++q) wb[q] = Wbt[c0 + q * 16 + cl];
  }

  // ---- in-kernel basemat -> LDS (registers freed after this block) ----
  {
    const size_t xoff = ((size_t)((pg << 4) + cl)) * 64 + kg;   // row = own point
    short8 xa0h = *(const short8*)(Xh + xoff);
    short8 xa1h = *(const short8*)(Xh + xoff + 32);
    short8 xa0l = *(const short8*)(Xl + xoff);
    short8 xa1l = *(const short8*)(Xl + xoff + 32);
#pragma unroll
    for (int q = 0; q < 4; ++q) {
      f32x4 base = {0.f, 0.f, 0.f, 0.f};
      const int ct = wave * 4 + q;
      const size_t w0 = (((size_t)ct * 2 + 0) * 64 + lane) * 8;
      const size_t w1 = (((size_t)ct * 2 + 1) * 64 + lane) * 8;
      short8 p0h = *(const short8*)(Wph + w0);
      short8 p0l = *(const short8*)(Wpl + w0);
      short8 p1h = *(const short8*)(Wph + w1);
      short8 p1l = *(const short8*)(Wpl + w1);
      base = __builtin_amdgcn_mfma_f32_16x16x32_bf16(xa0l, p0h, base, 0, 0, 0);
      base = __builtin_amdgcn_mfma_f32_16x16x32_bf16(xa0h, p0l, base, 0, 0, 0);
      base = __builtin_amdgcn_mfma_f32_16x16x32_bf16(xa0h, p0h, base, 0, 0, 0);
      base = __builtin_amdgcn_mfma_f32_16x16x32_bf16(xa1l, p1h, base, 0, 0, 0);
      base = __builtin_amdgcn_mfma_f32_16x16x32_bf16(xa1h, p1l, base, 0, 0, 0);
      base = __builtin_amdgcn_mfma_f32_16x16x32_bf16(xa1h, p1h, base, 0, 0, 0);
#pragma unroll
      for (int i = 0; i < 4; ++i)
        lds_base[wave][((lane >> 4) << 2) + i][q * 16 + cl] = base[i];
    }
  }

  float P1[4] = {0.f, 0.f, 0.f, 0.f}, P2[4] = {0.f, 0.f, 0.f, 0.f};
  float PCx[4] = {0.f, 0.f, 0.f, 0.f};
  float PB1[4] = {0.f, 0.f, 0.f, 0.f}, PB2[4] = {0.f, 0.f, 0.f, 0.f};

  // pipeline prologue: idx for p0,p1; frags for p0
  int jn = idx[ib + 16 + cl];
  int j0 = idx[ib + cl];
  size_t ro = ((size_t)(pbase | j0) << 6) + kg;
  short8 a0h = *(const short8*)(Xh + ro);
  short8 a1h = *(const short8*)(Xh + ro + 32);
  short8 a0l = *(const short8*)(Xl + ro);
  short8 a1l = *(const short8*)(Xl + ro + 32);

  for (int pp = 0; pp < 16; ++pp) {
    const int p = (pg << 4) | pp;
    int jf = 0;
    if (pp < 14) jf = idx[ib + ((pp + 2) << 4) + cl];
    short8 n0h, n1h, n0l, n1l;
    if (pp < 15) {
      size_t rn = ((size_t)(pbase | jn) << 6) + kg;
      n0h = *(const short8*)(Xh + rn);
      n1h = *(const short8*)(Xh + rn + 32);
      n0l = *(const short8*)(Xl + rn);
      n1l = *(const short8*)(Xl + rn + 32);
    }
    float dx0, dy0, dz0, dx1, dy1, dz1, dx2, dy2, dz2, dx3, dy3, dz3;
    if (HAS_PTS) {
      const int4 j4 = *(const int4*)(idx + (p << 4) + ((lane >> 4) << 2));
      const float4 pc = pack[p];
      const float4 q0 = pack[pbase | j4.x];
      const float4 q1 = pack[pbase | j4.y];
      const float4 q2 = pack[pbase | j4.z];
      const float4 q3 = pack[pbase | j4.w];
      dx0 = q0.x - pc.x; dy0 = q0.y - pc.y; dz0 = q0.z - pc.z;
      dx1 = q1.x - pc.x; dy1 = q1.y - pc.y; dz1 = q1.z - pc.z;
      dx2 = q2.x - pc.x; dy2 = q2.y - pc.y; dz2 = q2.z - pc.z;
      dx3 = q3.x - pc.x; dy3 = q3.y - pc.y; dz3 = q3.z - pc.z;
    }
    f32x4 acc[4];
#pragma unroll
    for (int q = 0; q < 4; ++q) {
      acc[q][0] = 0.f; acc[q][1] = 0.f; acc[q][2] = 0.f; acc[q][3] = 0.f;
    }
#pragma unroll
    for (int q = 0; q < 4; ++q) {
      acc[q] = __builtin_amdgcn_mfma_f32_16x16x32_bf16(a0l, bh[q][0], acc[q], 0, 0, 0);
      acc[q] = __builtin_amdgcn_mfma_f32_16x16x32_bf16(a1l, bh[q][1], acc[q], 0, 0, 0);
      acc[q] = __builtin_amdgcn_mfma_f32_16x16x32_bf16(a0h, blo[q][0], acc[q], 0, 0, 0);
      acc[q] = __builtin_amdgcn_mfma_f32_16x16x32_bf16(a1h, blo[q][1], acc[q], 0, 0, 0);
      acc[q] = __builtin_amdgcn_mfma_f32_16x16x32_bf16(a0h, bh[q][0], acc[q], 0, 0, 0);
      acc[q] = __builtin_amdgcn_mfma_f32_16x16x32_bf16(a1h, bh[q][1], acc[q], 0, 0, 0);
    }
    if (HAS_PTS) {
#pragma unroll
      for (int q = 0; q < 4; ++q) {
        acc[q][0] += dx0 * wb[q].x + dy0 * wb[q].y + dz0 * wb[q].z;
        acc[q][1] += dx1 * wb[q].x + dy1 * wb[q].y + dz1 * wb[q].z;
        acc[q][2] += dx2 * wb[q].x + dy2 * wb[q].y + dz2 * wb[q].z;
        acc[q][3] += dx3 * wb[q].x + dy3 * wb[q].y + dz3 * wb[q].z;
      }
    }
#pragma unroll
    for (int q = 0; q < 4; ++q) {
      float s1p = acc[q][0] + acc[q][1] + acc[q][2] + acc[q][3];
      float s2p = acc[q][0] * acc[q][0] + acc[q][1] * acc[q][1]
                + acc[q][2] * acc[q][2] + acc[q][3] * acc[q][3];
      float mx = fmaxf(fmaxf(acc[q][0], acc[q][1]), fmaxf(acc[q][2], acc[q][3]));
      mx = fmaxf(mx, __shfl_xor(mx, 16));
      mx = fmaxf(mx, __shfl_xor(mx, 32));
      float bb = lds_base[wave][pp][q * 16 + cl];
      if (lane < 16) out[(size_t)p * 256 + c0 + q * 16 + cl] = mx + bb;
      P1[q] += s1p;
      P2[q] += s2p;
      PCx[q] = fmaf(bb, s1p, PCx[q]);
      PB1[q] += bb;
      PB2[q] = fmaf(bb, bb, PB2[q]);
    }
    a0h = n0h; a1h = n1h; a0l = n0l; a1l = n1l;
    jn = jf;
  }
#pragma unroll
  for (int q = 0; q < 4; ++q) {
    float p1 = P1[q]; p1 += __shfl_xor(p1, 16); p1 += __shfl_xor(p1, 32);
    float p2 = P2[q]; p2 += __shfl_xor(p2, 16); p2 += __shfl_xor(p2, 32);
    float pc = PCx[q]; pc += __shfl_xor(pc, 16); pc += __shfl_xor(pc, 32);
    if (lane < 16) {
      atomicAdd(&stats[c0 + q * 16 + lane], p1 + 16.f * PB1[q]);
      atomicAdd(&stats[256 + c0 + q * 16 + lane], p2 + 2.f * pc + 16.f * PB2[q]);
    }
  }
}

// ---------------------------------------------------------------------------
// agg_pack (validated r10-r14): bn_relu(max over 16 nb) -> packed hi/lo.
// ---------------------------------------------------------------------------
template <int LGC>
__global__ __launch_bounds__(256) void agg_pack_kernel(
    const float* __restrict__ X, const int* __restrict__ idx,
    const float* __restrict__ stats, float inv_cnt,
    unsigned short* __restrict__ ph, unsigned short* __restrict__ pl) {
  const int C = 1 << LGC;
  const int xcd = blockIdx.x & 7, bat = xcd >> 1;
  const int j = ((blockIdx.x >> 3) << 1) | (xcd & 1);
  const int rows_per_block = 256 >> (LGC - 2);
  const int r = bat * 4096 + j * rows_per_block + (threadIdx.x >> (LGC - 2));
  const int cq = threadIdx.x & ((C >> 2) - 1);
  const int base = bat << 12;
  const int* ip = idx + (size_t)r * KSN;
  float4 mx = make_float4(-FLT_MAX, -FLT_MAX, -FLT_MAX, -FLT_MAX);
#pragma unroll
  for (int k = 0; k < KSN; ++k) {
    int jj = ip[k];
    const float4 v = *reinterpret_cast<const float4*>(X + (size_t)(base + jj) * C + cq * 4);
    mx.x = fmaxf(mx.x, v.x); mx.y = fmaxf(mx.y, v.y);
    mx.z = fmaxf(mx.z, v.z); mx.w = fmaxf(mx.w, v.w);
  }
  const int c = cq * 4;
  const float4 sa = *reinterpret_cast<const float4*>(stats + c);
  const float4 sb = *reinterpret_cast<const float4*>(stats + C + c);
  float m0 = sa.x * inv_cnt, m1 = sa.y * inv_cnt, m2 = sa.z * inv_cnt, m3 = sa.w * inv_cnt;
  float o0 = fmaxf((mx.x - m0) * rsqrtf(fmaxf(sb.x * inv_cnt - m0 * m0, 0.f) + EPSBN), 0.f);
  float o1 = fmaxf((mx.y - m1) * rsqrtf(fmaxf(sb.y * inv_cnt - m1 * m1, 0.f) + EPSBN), 0.f);
  float o2 = fmaxf((mx.z - m2) * rsqrtf(fmaxf(sb.z * inv_cnt - m2 * m2, 0.f) + EPSBN), 0.f);
  float o3 = fmaxf((mx.w - m3) * rsqrtf(fmaxf(sb.w * inv_cnt - m3 * m3, 0.f) + EPSBN), 0.f);
  short4v H, L;
  H.x = (short)f2bf(o0); L.x = (short)f2bf(o0 - bf2f((unsigned short)H.x));
  H.y = (short)f2bf(o1); L.y = (short)f2bf(o1 - bf2f((unsigned short)H.y));
  H.z = (short)f2bf(o2); L.z = (short)f2bf(o2 - bf2f((unsigned short)H.z));
  H.w = (short)f2bf(o3); L.w = (short)f2bf(o3 - bf2f((unsigned short)H.w));
  const int NK = C >> 5;
  const int rt = r >> 4, rl = r & 15, ks = c >> 5, kl = c & 31;
  const size_t dst = (((size_t)rt * NK + ks) * 64 + (((kl >> 3) << 4) | rl)) * 8 + (kl & 7);
  *(short4v*)(ph + dst) = H;
  *(short4v*)(pl + dst) = L;
}

// ---------------------------------------------------------------------------
// MFMA GEMM (validated r7-r14): wave = 64 rows x 64 cols, acc[4][4].
// ---------------------------------------------------------------------------
template <int AMODE, bool DOMAX, bool BIAS>
__global__ __launch_bounds__(256) void gemm_mfma_kernel(
    const unsigned short* __restrict__ Ah, const unsigned short* __restrict__ Al,
    const unsigned short* __restrict__ Wh, const unsigned short* __restrict__ Wl,
    float* __restrict__ Y, float* __restrict__ pmax, float* __restrict__ stats,
    const float* __restrict__ gbias,
    int K, int C) {
  __shared__ float red1[4][64], red2[4][64], redm[4][64];
  const int wave = threadIdx.x >> 6, lane = threadIdx.x & 63;
  const int rtb = blockIdx.x * 16 + wave * 4;
  const int c0  = blockIdx.y * 64;
  const int ct0 = blockIdx.y * 4;
  const int NK  = K >> 5;
  const int bat = blockIdx.x >> 4;
  f32x4 acc[4][4];
#pragma unroll
  for (int r = 0; r < 4; ++r)
#pragma unroll
    for (int cc = 0; cc < 4; ++cc) {
      acc[r][cc][0] = 0.f; acc[r][cc][1] = 0.f; acc[r][cc][2] = 0.f; acc[r][cc][3] = 0.f;
    }
  const int lhalf = (lane >> 4) << 3;
  for (int ks = 0; ks < NK; ++ks) {
    short8 ah[4], al[4];
    if (AMODE == 1) {
#pragma unroll
      for (int r = 0; r < 4; ++r) {
        const size_t aoff = ((size_t)((rtb + r) * 16 + (lane & 15))) * 64 + ks * 32 + lhalf;
        ah[r] = *(const short8*)(Ah + aoff);
        al[r] = *(const short8*)(Al + aoff);
      }
    } else {
#pragma unroll
      for (int r = 0; r < 4; ++r) {
        const size_t aoff = (((size_t)(rtb + r) * NK + ks) * 64 + lane) * 8;
        ah[r] = *(const short8*)(Ah + aoff);
        al[r] = *(const short8*)(Al + aoff);
      }
    }
#pragma unroll
    for (int cc = 0; cc < 4; ++cc) {
      const size_t woff = (((size_t)(ct0 + cc) * NK + ks) * 64 + lane) * 8;
      short8 bh = *(const short8*)(Wh + woff);
      short8 bl = *(const short8*)(Wl + woff);
#pragma unroll
      for (int r = 0; r < 4; ++r) {
        acc[r][cc] = __builtin_amdgcn_mfma_f32_16x16x32_bf16(al[r], bh, acc[r][cc], 0, 0, 0);
        acc[r][cc] = __builtin_amdgcn_mfma_f32_16x16x32_bf16(ah[r], bl, acc[r][cc], 0, 0, 0);
        acc[r][cc] = __builtin_amdgcn_mfma_f32_16x16x32_bf16(ah[r], bh, acc[r][cc], 0, 0, 0);
      }
    }
  }
#pragma unroll
  for (int cc = 0; cc < 4; ++cc) {
    float bv = 0.f;
    if (BIAS) bv = gbias[(size_t)bat * C + c0 + cc * 16 + (lane & 15)];
    float s1 = 0.f, s2 = 0.f, mm = -FLT_MAX;
#pragma unroll
    for (int r = 0; r < 4; ++r) {
#pragma unroll
      for (int i = 0; i < 4; ++i) {
        float v = acc[r][cc][i] + bv;
        if (!DOMAX)
          Y[(size_t)((rtb + r) * 16 + ((lane >> 4) << 2) + i) * C + c0 + cc * 16 + (lane & 15)] = v;
        s1 += v; s2 = fmaf(v, v, s2); mm = fmaxf(mm, v);
      }
    }
    s1 += __shfl_xor(s1, 16); s1 += __shfl_xor(s1, 32);
    s2 += __shfl_xor(s2, 16); s2 += __shfl_xor(s2, 32);
    mm = fmaxf(mm, __shfl_xor(mm, 16)); mm = fmaxf(mm, __shfl_xor(mm, 32));
    if (lane < 16) {
      red1[wave][cc * 16 + lane] = s1;
      red2[wave][cc * 16 + lane] = s2;
      if (DOMAX) redm[wave][cc * 16 + lane] = mm;
    }
  }
  __syncthreads();
  if (threadIdx.x < 64) {
    const int t = threadIdx.x;
    float a = red1[0][t] + red1[1][t] + red1[2][t] + red1[3][t];
    float b = red2[0][t] + red2[1][t] + red2[2][t] + red2[3][t];
    atomicAdd(&stats[c0 + t], a);
    atomicAdd(&stats[C + c0 + t], b);
    if (DOMAX) {
      float mm = fmaxf(fmaxf(redm[0][t], redm[1][t]), fmaxf(redm[2][t], redm[3][t]));
      pmax[(size_t)blockIdx.x * C + c0 + t] = mm;
    }
  }
}

// ---------------------------------------------------------------------------
// fin_g + gb11 fused (validated r12-r14).
// ---------------------------------------------------------------------------
__global__ __launch_bounds__(256) void fing_gb_kernel(const float* __restrict__ pmax,
                                                      const float* __restrict__ S7,
                                                      const float* __restrict__ W11,
                                                      float* __restrict__ gb) {
  __shared__ float g_lds[1024];
  const int t = threadIdx.x;
  const int b = blockIdx.x >> 1, ch = blockIdx.x & 1;
  const float inv = 1.0f / 16384.0f;
#pragma unroll
  for (int kk = 0; kk < 4; ++kk) {
    int c = kk * 256 + t;
    float m = S7[c] * inv;
    float v = fmaxf(S7[1024 + c] * inv - m * m, 0.0f);
    float rs = rsqrtf(v + EPSBN);
    float mx = -FLT_MAX;
    for (int s = 0; s < 16; ++s) mx = fmaxf(mx, pmax[(size_t)(b * 16 + s) * 1024 + c]);
    g_lds[c] = fmaxf((mx - m) * rs, 0.0f);
  }
  __syncthreads();
  const int c_out = ch * 256 + t;
  float acc = 0.f;
#pragma unroll 8
  for (int k = 0; k < 1024; ++k) acc = fmaf(g_lds[k], W11[(size_t)k * 512 + c_out], acc);
  gb[b * 512 + c_out] = acc;
}

// final13 with fused BN(h12) (validated r10-r14)
__global__ __launch_bounds__(256) void final13_kernel(const float* __restrict__ h,
                                                      const float* __restrict__ S9,
                                                      const float* __restrict__ W,
                                                      float* __restrict__ out) {
  __shared__ float wl[256 * 13];
  __shared__ float ms[256], rs[256];
  const int t = threadIdx.x;
  {
    const float inv = 1.0f / RN;
    float m = S9[t] * inv;
    float v = fmaxf(S9[256 + t] * inv - m * m, 0.0f);
    ms[t] = m; rs[t] = rsqrtf(v + EPSBN);
#pragma unroll
    for (int i = 0; i < 13; ++i) wl[t * 13 + i] = W[t * 13 + i];
  }
  __syncthreads();
  const int r = blockIdx.x * 16 + (t >> 4);
  const int c = t & 15;
  const int ci = (c < 13) ? c : 0;
  const float* hr = h + (size_t)r * 256;
  float acc = 0.0f;
  for (int k = 0; k < 256; ++k) {
    float x = fmaxf((hr[k] - ms[k]) * rs[k], 0.0f);
    acc = fmaf(x, wl[k * 13 + ci], acc);
  }
  if (c < 13) {
    int b = r >> 12, n = r & 4095;
    out[(size_t)b * 13 * NN + (size_t)c * NN + n] = acc;
  }
}

// ---------------------------------------------------------------------------
extern "C" void kernel_launch(void* const* d_in, const int* in_sizes, int n_in,
                              void* d_out, int out_size, void* d_ws, size_t ws_size,
                              hipStream_t stream) {
  (void)in_sizes; (void)n_in; (void)out_size; (void)ws_size;
  const float* data = (const float*)d_in[0];
  const float* W_fc = (const float*)d_in[1];
  const float* b_fc = (const float*)d_in[2];
  const float* W1   = (const float*)d_in[3];
  const float* W2   = (const float*)d_in[4];
  const float* W3   = (const float*)d_in[5];
  const float* W4   = (const float*)d_in[6];
  const float* W5   = (const float*)d_in[7];
  const float* W6   = (const float*)d_in[8];
  const float* W10  = (const float*)d_in[9];
  const float* W11  = (const float*)d_in[10];
  const float* W12  = (const float*)d_in[11];
  const float* W13  = (const float*)d_in[12];
  float* out = (float*)d_out;

  float* ws  = (float*)d_ws;
  int*   idx = (int*)d_ws;
  size_t o = 262144;
  float* x0   = ws + o; o += (size_t)RN * 64;     // dead fp32; hosts x12l overlay
  float* x1v  = ws + o; o += (size_t)RN * 64;
  float* x2v  = ws + o; o += (size_t)RN * 64;
  float* bufA = ws + o; o += (size_t)RN * 256;
  float* bufB = ws + o; o += (size_t)RN * 256;    // hosts h11l overlay
  float* bufC = ws + o; o += (size_t)RN * 64;
  float* pmax = ws + o; o += (size_t)64 * 1024;
  float* h11  = ws + o; o += (size_t)RN * 512;
  float* h12  = ws + o; o += (size_t)RN * 256;
  float* stats = ws + o; o += 8192;
  float4* pack = (float4*)(ws + o); o += (size_t)RN * 4;
  unsigned short* xbh = (unsigned short*)(ws + o); o += (size_t)RN * 32;
  unsigned short* xbl = (unsigned short*)(ws + o); o += (size_t)RN * 32;
  unsigned short* W1mh = (unsigned short*)(ws + o); o += 8192;
  unsigned short* W1ml = (unsigned short*)(ws + o); o += 8192;
  unsigned short* W4mh = (unsigned short*)(ws + o); o += 8192;
  unsigned short* W4ml = (unsigned short*)(ws + o); o += 8192;
  float4* W1bt = (float4*)(ws + o); o += 1024;
  unsigned short* W10h = (unsigned short*)(ws + o); o += 65536;
  unsigned short* W10l = (unsigned short*)(ws + o); o += 65536;
  unsigned short* W11xh = (unsigned short*)(ws + o); o += 32768;
  unsigned short* W11xl = (unsigned short*)(ws + o); o += 32768;
  unsigned short* W12h = (unsigned short*)(ws + o); o += 65536;
  unsigned short* W12l = (unsigned short*)(ws + o); o += 65536;
  float* gb = ws + o; o += 2048;
  unsigned short* W1ph = (unsigned short*)(ws + o); o += 8192;
  unsigned short* W1pl = (unsigned short*)(ws + o); o += 8192;
  unsigned short* W4ph = (unsigned short*)(ws + o); o += 8192;
  unsigned short* W4pl = (unsigned short*)(ws + o); o += 8192;
  unsigned short* W2h  = (unsigned short*)(ws + o); o += 8192;
  unsigned short* W2l  = (unsigned short*)(ws + o); o += 8192;
  unsigned short* W3h  = (unsigned short*)(ws + o); o += 2048;
  unsigned short* W3l  = (unsigned short*)(ws + o); o += 2048;
  unsigned short* W5h  = (unsigned short*)(ws + o); o += 8192;
  unsigned short* W5l  = (unsigned short*)(ws + o); o += 8192;
  unsigned short* W6h  = (unsigned short*)(ws + o); o += 2048;
  unsigned short* W6l  = (unsigned short*)(ws + o); o += 2048;
  float* gpart = ws + o; o += 64 * 54;
  // overlays on dead buffers:
  unsigned short* x12h = (unsigned short*)bufC;
  unsigned short* x12l = (unsigned short*)x0;
  unsigned short* h11h = (unsigned short*)bufA;
  unsigned short* h11l = (unsigned short*)bufB;
  unsigned short* aggh = (unsigned short*)h11;
  unsigned short* aggl = (unsigned short*)h11 + (size_t)RN * 256;

  float* S0 = stats;          // 64 (fc)
  float* S1 = stats + 128;    // 256 (edge1)
  float* S2 = stats + 640;    // 64  (W2)
  float* S3 = stats + 768;    // 64  (W3)
  float* S4 = stats + 896;    // 256 (edge2)
  float* S5 = stats + 1408;   // 64  (W5)
  float* S6 = stats + 1536;   // 64  (W6)
  float* S7 = stats + 1664;   // 1024 (W10)
  float* S8 = stats + 3712;   // 512 (W11)
  float* S9 = stats + 4736;   // 256 (W12)

  hipMemsetAsync(stats, 0, 8192 * sizeof(float), stream);

  prepgram_kernel<<<64, 256, 0, stream>>>(data, pack, gpart);
  fcstats_kernel<<<1, 64, 0, stream>>>(gpart, W_fc, b_fc, S0);

  // MEGA: knn (4096 blocks) + fc_bnpack (4096) + megaprep (1632)
  mega_kernel<<<9824, 256, 0, stream>>>(
      pack, idx, data, W_fc, b_fc, S0, xbh, xbl,
      W1, W4, W2, W3, W5, W6, W10, W11, W12,
      W1mh, W1ml, W1bt, W4mh, W4ml,
      W1ph, W1pl, W4ph, W4pl, W2h, W2l, W3h, W3l, W5h, W5l, W6h, W6l,
      W10h, W10l, W11xh, W11xl, W12h, W12l);

  // edge conv 1 (basemat in-kernel -> LDS; A-prefetch pipeline)
  edge_mfma_kernel<true><<<1024, 256, 0, stream>>>(
      xbh, xbl, idx, pack, W1mh, W1ml, W1ph, W1pl, W1bt, bufA, S1);

  // graph conv 1
  agg_pack_kernel<8><<<4096, 256, 0, stream>>>(bufA, idx, S1, 1.0f / (RN * 16), aggh, aggl);
  gemm_mfma_kernel<0, false, false><<<dim3(64, 1), 256, 0, stream>>>(
      aggh, aggl, W2h, W2l, bufC, nullptr, S2, nullptr, 256, 64);

  // graph conv 2
  agg_pack_kernel<6><<<1024, 256, 0, stream>>>(bufC, idx, S2, 1.0f / RN, aggh, aggl);
  gemm_mfma_kernel<0, false, false><<<dim3(64, 1), 256, 0, stream>>>(
      aggh, aggl, W3h, W3l, x1v, nullptr, S3, nullptr, 64, 64);
  bn_normpack_kernel<<<RN * 64 / 256, 256, 0, stream>>>(x1v, S3, xbh, xbl);

  // edge conv 2 (no pts; basemat in-kernel -> LDS; A-prefetch pipeline)
  edge_mfma_kernel<false><<<1024, 256, 0, stream>>>(
      xbh, xbl, idx, pack, W4mh, W4ml, W4ph, W4pl, nullptr, bufA, S4);

  // graph conv 3
  agg_pack_kernel<8><<<4096, 256, 0, stream>>>(bufA, idx, S4, 1.0f / (RN * 16), aggh, aggl);
  gemm_mfma_kernel<0, false, false><<<dim3(64, 1), 256, 0, stream>>>(
      aggh, aggl, W5h, W5l, bufC, nullptr, S5, nullptr, 256, 64);

  // graph conv 4 -> x2v raw (+S6); bn fused into pack_x12
  agg_pack_kernel<6><<<1024, 256, 0, stream>>>(bufC, idx, S5, 1.0f / RN, aggh, aggl);
  gemm_mfma_kernel<0, false, false><<<dim3(64, 1), 256, 0, stream>>>(
      aggh, aggl, W6h, W6l, x2v, nullptr, S6, nullptr, 64, 64);

  // pack [x1|bn(x2)]
  pack_x12_kernel<<<RN * 128 / 256, 256, 0, stream>>>(x1v, x2v, S6, x12h, x12l);

  // W10 path
  gemm_mfma_kernel<0, true, false><<<dim3(64, 16), 256, 0, stream>>>(
      x12h, x12l, W10h, W10l, nullptr, pmax, S7, nullptr, 128, 1024);

  // fused fin_g + gb11
  fing_gb_kernel<<<8, 256, 0, stream>>>(pmax, S7, W11, gb);

  // W11: K=128 MFMA gemm + per-batch g-bias
  gemm_mfma_kernel<0, false, true><<<dim3(64, 8), 256, 0, stream>>>(
      x12h, x12l, W11xh, W11xl, h11, nullptr, S8, gb, 128, 512);
  bn_pack_kernel<<<RN * 512 / 256, 256, 0, stream>>>(h11, S8, h11h, h11l);

  // W12 -> h12 raw (+S9); bn fused into final13
  gemm_mfma_kernel<0, false, false><<<dim3(64, 4), 256, 0, stream>>>(
      h11h, h11l, W12h, W12l, h12, nullptr, S9, nullptr, 512, 256);

  final13_kernel<<<RN / 16, 256, 0, stream>>>(h12, S9, W13, out);
}